// Round 1
// baseline (1582.067 us; speedup 1.0000x reference)
//
#include <hip/hip_runtime.h>
#include <stdint.h>

#define D_MODEL 2048
#define NH 16
#define DH 128
#define BATCH 4
#define SEQ 2048
#define MTOT (BATCH*SEQ)   // 8192

typedef __bf16 bf16x8 __attribute__((ext_vector_type(8)));
typedef float f32x4 __attribute__((ext_vector_type(4)));
typedef short short8 __attribute__((ext_vector_type(8)));

static __device__ __forceinline__ unsigned short f2bf(float f) {
  union { float f; unsigned int u; } v; v.f = f;
  return (unsigned short)((v.u + 0x7FFFu + ((v.u >> 16) & 1u)) >> 16);
}

// ---------------- fp32 -> bf16 conversion ----------------
__global__ __launch_bounds__(256) void cvt_bf16_k(const float* __restrict__ in,
                                                  unsigned short* __restrict__ out, int n) {
  int i = (blockIdx.x * 256 + threadIdx.x) * 8;
  if (i >= n) return;
  float4 a = *(const float4*)(in + i);
  float4 b = *(const float4*)(in + i + 4);
  union { unsigned short u[8]; short8 v; } o;
  o.u[0] = f2bf(a.x); o.u[1] = f2bf(a.y); o.u[2] = f2bf(a.z); o.u[3] = f2bf(a.w);
  o.u[4] = f2bf(b.x); o.u[5] = f2bf(b.y); o.u[6] = f2bf(b.z); o.u[7] = f2bf(b.w);
  *(short8*)(out + i) = o.v;
}

// ---------------- GEMM: C[M,N] = A[M,K] * B[N,K]^T  (both row-major, bf16) ----------------
// 128x128 tile, BK=64, 256 threads = 4 waves in 2x2; each wave 64x64 = 4x4 frags of 16x16x32.
template<bool OUT_BF16, bool ADD_BIAS>
__global__ __launch_bounds__(256) void gemm_bt(const unsigned short* __restrict__ A,
                                               const unsigned short* __restrict__ B,
                                               void* __restrict__ C,
                                               const float* __restrict__ bias,
                                               int M, int N, int K) {
  __shared__ __align__(16) unsigned short As[128 * 64];
  __shared__ __align__(16) unsigned short Bs[128 * 64];
  const int tid = threadIdx.x;
  const int lane = tid & 63;
  const int l15 = lane & 15, l4 = lane >> 4;
  const int w = tid >> 6, wr = w >> 1, wc = w & 1;
  const int bm = blockIdx.x, bn = blockIdx.y;

  f32x4 acc[4][4] = {};

  for (int k0 = 0; k0 < K; k0 += 64) {
    __syncthreads();
#pragma unroll
    for (int it = 0; it < 4; ++it) {
      int c = tid + it * 256;
      int row = c >> 3, kb = c & 7;   // 8 x 16B chunks per 64-col row
      const unsigned short* ga = A + (size_t)(bm * 128 + row) * K + k0 + kb * 8;
      __builtin_amdgcn_global_load_lds((const __attribute__((address_space(1))) void*)ga,
                                       (__attribute__((address_space(3))) void*)(As + c * 8),
                                       16, 0, 0);
      const unsigned short* gb = B + (size_t)(bn * 128 + row) * K + k0 + kb * 8;
      __builtin_amdgcn_global_load_lds((const __attribute__((address_space(1))) void*)gb,
                                       (__attribute__((address_space(3))) void*)(Bs + c * 8),
                                       16, 0, 0);
    }
    asm volatile("s_waitcnt vmcnt(0)" ::: "memory");
    __syncthreads();
#pragma unroll
    for (int ks = 0; ks < 2; ++ks) {
      bf16x8 af[4], bfr[4];
#pragma unroll
      for (int mi = 0; mi < 4; ++mi)
        af[mi] = *(const bf16x8*)&As[(wr * 64 + mi * 16 + l15) * 64 + ks * 32 + l4 * 8];
#pragma unroll
      for (int ni = 0; ni < 4; ++ni)
        bfr[ni] = *(const bf16x8*)&Bs[(wc * 64 + ni * 16 + l15) * 64 + ks * 32 + l4 * 8];
#pragma unroll
      for (int mi = 0; mi < 4; ++mi)
#pragma unroll
        for (int ni = 0; ni < 4; ++ni)
          acc[mi][ni] = __builtin_amdgcn_mfma_f32_16x16x32_bf16(af[mi], bfr[ni], acc[mi][ni], 0, 0, 0);
    }
  }

  const int row0 = bm * 128 + wr * 64;
  const int col0 = bn * 128 + wc * 64;
#pragma unroll
  for (int mi = 0; mi < 4; ++mi) {
#pragma unroll
    for (int ni = 0; ni < 4; ++ni) {
      int col = col0 + ni * 16 + l15;
#pragma unroll
      for (int r = 0; r < 4; ++r) {
        int row = row0 + mi * 16 + l4 * 4 + r;
        float v = acc[mi][ni][r];
        if (ADD_BIAS) v += bias[col];
        if (OUT_BF16)
          ((unsigned short*)C)[(size_t)row * N + col] = f2bf(v);
        else
          ((float*)C)[(size_t)row * N + col] = v;
      }
    }
  }
}

// ---------------- causal flash attention ----------------
// grid: (SEQ/64, BATCH*NH). block = 256 threads = 4 waves; wave w owns q rows [qt*64+w*16, +16).
__global__ __launch_bounds__(256) void attn_k(const unsigned short* __restrict__ Q,
                                              const unsigned short* __restrict__ K,
                                              const unsigned short* __restrict__ V,
                                              unsigned short* __restrict__ O) {
  __shared__ __align__(16) unsigned short Ks[64 * 128];   // [key][kd], XOR-swizzled
  __shared__ __align__(16) unsigned short Vt[128 * 64];   // [dh][key], XOR-swizzled
  __shared__ __align__(16) unsigned short Pl[4 * 16 * 64];// per-wave P tile, swizzled

  const int tid = threadIdx.x;
  const int lane = tid & 63;
  const int l15 = lane & 15, l4 = lane >> 4;
  const int w = tid >> 6;

  const int qt = blockIdx.x;
  const int bh = blockIdx.y;
  const int b = bh >> 4, h = bh & 15;

  const size_t base = (size_t)b * SEQ * D_MODEL + (size_t)h * DH;
  const int qrow_w = qt * 64 + w * 16;   // first q row of this wave (seq index)

  // Q fragments in registers (row = l15, k = kk*32 + l4*8 + j)
  bf16x8 qf[4];
  const unsigned short* qptr = Q + base + (size_t)(qrow_w + l15) * D_MODEL;
#pragma unroll
  for (int kk = 0; kk < 4; ++kk)
    qf[kk] = *(const bf16x8*)(qptr + kk * 32 + l4 * 8);

  f32x4 acc_o[8] = {};
  float m_run[4] = {-3.4028235e38f, -3.4028235e38f, -3.4028235e38f, -3.4028235e38f};
  float l_run[4] = {0.f, 0.f, 0.f, 0.f};
  const float SC = 0.12751743f;  // (1/sqrt(128)) * log2(e)

  for (int kt = 0; kt <= qt; ++kt) {
    const int kv0 = kt * 64;
    __syncthreads();
    // stage K (swizzled row-major) and V (transposed, swizzled)
#pragma unroll
    for (int it = 0; it < 4; ++it) {
      int c = tid + it * 256;
      int key = c >> 4, kb = c & 15;   // 16 x 16B chunks per 128-dim row
      short8 kv = *(const short8*)(K + base + (size_t)(kv0 + key) * D_MODEL + kb * 8);
      *(short8*)&Ks[key * 128 + ((kb * 8) ^ ((key & 7) << 3))] = kv;
      union { short8 v; unsigned short u[8]; } uv;
      uv.v = *(const short8*)(V + base + (size_t)(kv0 + key) * D_MODEL + kb * 8);
#pragma unroll
      for (int j = 0; j < 8; ++j) {
        int dh = kb * 8 + j;
        Vt[dh * 64 + (key ^ ((dh & 7) << 3))] = uv.u[j];
      }
    }
    __syncthreads();

    // S = Q K^T : 4 key-subtiles of 16, each 4 MFMA over Dh=128
    f32x4 sacc[4] = {};
#pragma unroll
    for (int st = 0; st < 4; ++st) {
      int key = st * 16 + l15;
#pragma unroll
      for (int kk = 0; kk < 4; ++kk) {
        bf16x8 kf = *(const bf16x8*)&Ks[key * 128 + ((kk * 32 + l4 * 8) ^ ((key & 7) << 3))];
        sacc[st] = __builtin_amdgcn_mfma_f32_16x16x32_bf16(qf[kk], kf, sacc[st], 0, 0, 0);
      }
    }

    // online softmax (rows r: q = qrow_w + l4*4 + r ; col = l15 within subtile)
    const bool diag = (kt == qt);
    float sc[4][4];
#pragma unroll
    for (int st = 0; st < 4; ++st)
#pragma unroll
      for (int r = 0; r < 4; ++r) {
        float s = sacc[st][r];
        if (diag) {
          int key = kv0 + st * 16 + l15;
          int qr = qrow_w + l4 * 4 + r;
          if (key > qr) s = -3.4028235e38f;
        }
        sc[st][r] = s;
      }
    float rmax[4];
#pragma unroll
    for (int r = 0; r < 4; ++r) {
      float t = fmaxf(fmaxf(sc[0][r], sc[1][r]), fmaxf(sc[2][r], sc[3][r]));
#pragma unroll
      for (int msk = 1; msk < 16; msk <<= 1)
        t = fmaxf(t, __shfl_xor(t, msk));
      rmax[r] = t;
    }
    float p[4][4], scl[4];
#pragma unroll
    for (int r = 0; r < 4; ++r) {
      float nm = fmaxf(m_run[r], rmax[r]);
      scl[r] = exp2f((m_run[r] - nm) * SC);
      m_run[r] = nm;
      float ps = 0.f;
#pragma unroll
      for (int st = 0; st < 4; ++st) {
        float pv = exp2f((sc[st][r] - nm) * SC);
        p[st][r] = pv;
        ps += pv;
      }
      l_run[r] = l_run[r] * scl[r] + ps;
    }
    // rescale accumulator
#pragma unroll
    for (int df = 0; df < 8; ++df) {
      f32x4 t = acc_o[df];
      t[0] *= scl[0]; t[1] *= scl[1]; t[2] *= scl[2]; t[3] *= scl[3];
      acc_o[df] = t;
    }
    // P -> per-wave LDS (bf16, swizzled): row q=l4*4+r, col k=st*16+l15
#pragma unroll
    for (int st = 0; st < 4; ++st)
#pragma unroll
      for (int r = 0; r < 4; ++r) {
        int q = l4 * 4 + r;
        int k = st * 16 + l15;
        Pl[w * 1024 + q * 64 + (k ^ ((q & 7) << 3))] = f2bf(p[st][r]);
      }
    // O += P V : A-frag rows q=l15, k = keys; B-frag from Vt (contiguous keys)
#pragma unroll
    for (int ks = 0; ks < 2; ++ks) {
      bf16x8 pa = *(const bf16x8*)&Pl[w * 1024 + l15 * 64 + ((ks * 32 + l4 * 8) ^ ((l15 & 7) << 3))];
#pragma unroll
      for (int df = 0; df < 8; ++df) {
        int dh = df * 16 + l15;
        bf16x8 vb = *(const bf16x8*)&Vt[dh * 64 + ((ks * 32 + l4 * 8) ^ ((dh & 7) << 3))];
        acc_o[df] = __builtin_amdgcn_mfma_f32_16x16x32_bf16(pa, vb, acc_o[df], 0, 0, 0);
      }
    }
  }

  // finalize: reduce row sums across the 16 lanes, normalize, store bf16
  float linv[4];
#pragma unroll
  for (int r = 0; r < 4; ++r) {
    float t = l_run[r];
#pragma unroll
    for (int msk = 1; msk < 16; msk <<= 1)
      t += __shfl_xor(t, msk);
    linv[r] = 1.0f / t;
  }
#pragma unroll
  for (int df = 0; df < 8; ++df)
#pragma unroll
    for (int r = 0; r < 4; ++r) {
      int row = qrow_w + l4 * 4 + r;
      O[base + (size_t)row * D_MODEL + df * 16 + l15] = f2bf(acc_o[df][r] * linv[r]);
    }
}

// ---------------- launch ----------------
extern "C" void kernel_launch(void* const* d_in, const int* in_sizes, int n_in,
                              void* d_out, int out_size, void* d_ws, size_t ws_size,
                              hipStream_t stream) {
  const float* x  = (const float*)d_in[0];
  const float* Wq = (const float*)d_in[1];
  const float* Wk = (const float*)d_in[2];
  const float* Wv = (const float*)d_in[3];
  const float* Wo = (const float*)d_in[4];
  const float* bo = (const float*)d_in[5];
  float* out = (float*)d_out;

  unsigned short* ws = (unsigned short*)d_ws;
  const size_t XSZ = (size_t)MTOT * D_MODEL;     // 16,777,216
  const size_t WSZ = (size_t)D_MODEL * D_MODEL;  // 4,194,304
  unsigned short* xb  = ws;
  unsigned short* Wqb = xb + XSZ;
  unsigned short* Wkb = Wqb + WSZ;
  unsigned short* Wvb = Wkb + WSZ;
  unsigned short* Wob = Wvb + WSZ;
  unsigned short* Qb  = Wob + WSZ;
  unsigned short* Kb  = Qb + XSZ;
  unsigned short* Vb  = Kb + XSZ;
  unsigned short* AOb = xb;   // x no longer needed after projections

  // conversions
  cvt_bf16_k<<<(int)(XSZ / 8 / 256), 256, 0, stream>>>(x, xb, (int)XSZ);
  cvt_bf16_k<<<(int)(WSZ / 8 / 256), 256, 0, stream>>>(Wq, Wqb, (int)WSZ);
  cvt_bf16_k<<<(int)(WSZ / 8 / 256), 256, 0, stream>>>(Wk, Wkb, (int)WSZ);
  cvt_bf16_k<<<(int)(WSZ / 8 / 256), 256, 0, stream>>>(Wv, Wvb, (int)WSZ);
  cvt_bf16_k<<<(int)(WSZ / 8 / 256), 256, 0, stream>>>(Wo, Wob, (int)WSZ);

  dim3 gg(MTOT / 128, D_MODEL / 128);  // 64 x 16
  gemm_bt<true, false><<<gg, 256, 0, stream>>>(xb, Wqb, Qb, nullptr, MTOT, D_MODEL, D_MODEL);
  gemm_bt<true, false><<<gg, 256, 0, stream>>>(xb, Wkb, Kb, nullptr, MTOT, D_MODEL, D_MODEL);
  gemm_bt<true, false><<<gg, 256, 0, stream>>>(xb, Wvb, Vb, nullptr, MTOT, D_MODEL, D_MODEL);

  dim3 ga(SEQ / 64, BATCH * NH);       // 32 x 64
  attn_k<<<ga, 256, 0, stream>>>(Qb, Kb, Vb, AOb);

  gemm_bt<false, true><<<gg, 256, 0, stream>>>(AOb, Wob, out, bo, MTOT, D_MODEL, D_MODEL);
}

// Round 2
// 768.590 us; speedup vs baseline: 2.0584x; 2.0584x over previous
//
#include <hip/hip_runtime.h>
#include <stdint.h>

#define D_MODEL 2048
#define NH 16
#define DH 128
#define BATCH 4
#define SEQ 2048
#define MTOT (BATCH*SEQ)   // 8192

typedef __bf16 bf16x8 __attribute__((ext_vector_type(8)));
typedef float f32x4 __attribute__((ext_vector_type(4)));
typedef short short8 __attribute__((ext_vector_type(8)));

static __device__ __forceinline__ unsigned short f2bf(float f) {
  union { float f; unsigned int u; } v; v.f = f;
  return (unsigned short)((v.u + 0x7FFFu + ((v.u >> 16) & 1u)) >> 16);
}

// ---------------- fp32 -> bf16 conversion ----------------
__global__ __launch_bounds__(256) void cvt_bf16_k(const float* __restrict__ in,
                                                  unsigned short* __restrict__ out, int n) {
  int i = (blockIdx.x * 256 + threadIdx.x) * 8;
  if (i >= n) return;
  float4 a = *(const float4*)(in + i);
  float4 b = *(const float4*)(in + i + 4);
  union { unsigned short u[8]; short8 v; } o;
  o.u[0] = f2bf(a.x); o.u[1] = f2bf(a.y); o.u[2] = f2bf(a.z); o.u[3] = f2bf(a.w);
  o.u[4] = f2bf(b.x); o.u[5] = f2bf(b.y); o.u[6] = f2bf(b.z); o.u[7] = f2bf(b.w);
  *(short8*)(out + i) = o.v;
}

// ---------------- GEMM: C[M,N] = A[M,K] * B[N,K]^T  (both row-major, bf16) ----------------
// 128x128 tile, BK=64, 256 threads = 4 waves in 2x2; each wave 64x64 = 4x4 frags of 16x16x32.
// XCD-aware block swizzle (nwg = 64*16 = 1024, % 8 == 0 -> simple bijective form).
template<bool OUT_BF16, bool ADD_BIAS>
__global__ __launch_bounds__(256) void gemm_bt(const unsigned short* __restrict__ A,
                                               const unsigned short* __restrict__ B,
                                               void* __restrict__ C,
                                               const float* __restrict__ bias,
                                               int M, int N, int K) {
  __shared__ __align__(16) unsigned short As[128 * 64];
  __shared__ __align__(16) unsigned short Bs[128 * 64];
  const int tid = threadIdx.x;
  const int lane = tid & 63;
  const int l15 = lane & 15, l4 = lane >> 4;
  const int w = tid >> 6, wr = w >> 1, wc = w & 1;

  const int gx = gridDim.x;
  const int nwg = gx * gridDim.y;
  const int id = blockIdx.y * gx + blockIdx.x;
  const int cpx = nwg >> 3;
  const int swz = (id & 7) * cpx + (id >> 3);
  const int bm = swz % gx, bn = swz / gx;

  f32x4 acc[4][4] = {};

  for (int k0 = 0; k0 < K; k0 += 64) {
    __syncthreads();
#pragma unroll
    for (int it = 0; it < 4; ++it) {
      int c = tid + it * 256;
      int row = c >> 3, kb = c & 7;   // 8 x 16B chunks per 64-col row
      const unsigned short* ga = A + (size_t)(bm * 128 + row) * K + k0 + kb * 8;
      __builtin_amdgcn_global_load_lds((const __attribute__((address_space(1))) void*)ga,
                                       (__attribute__((address_space(3))) void*)(As + c * 8),
                                       16, 0, 0);
      const unsigned short* gb = B + (size_t)(bn * 128 + row) * K + k0 + kb * 8;
      __builtin_amdgcn_global_load_lds((const __attribute__((address_space(1))) void*)gb,
                                       (__attribute__((address_space(3))) void*)(Bs + c * 8),
                                       16, 0, 0);
    }
    asm volatile("s_waitcnt vmcnt(0)" ::: "memory");
    __syncthreads();
#pragma unroll
    for (int ks = 0; ks < 2; ++ks) {
      bf16x8 af[4], bfr[4];
#pragma unroll
      for (int mi = 0; mi < 4; ++mi)
        af[mi] = *(const bf16x8*)&As[(wr * 64 + mi * 16 + l15) * 64 + ks * 32 + l4 * 8];
#pragma unroll
      for (int ni = 0; ni < 4; ++ni)
        bfr[ni] = *(const bf16x8*)&Bs[(wc * 64 + ni * 16 + l15) * 64 + ks * 32 + l4 * 8];
#pragma unroll
      for (int mi = 0; mi < 4; ++mi)
#pragma unroll
        for (int ni = 0; ni < 4; ++ni)
          acc[mi][ni] = __builtin_amdgcn_mfma_f32_16x16x32_bf16(af[mi], bfr[ni], acc[mi][ni], 0, 0, 0);
    }
  }

  const int row0 = bm * 128 + wr * 64;
  const int col0 = bn * 128 + wc * 64;
#pragma unroll
  for (int mi = 0; mi < 4; ++mi) {
#pragma unroll
    for (int ni = 0; ni < 4; ++ni) {
      int col = col0 + ni * 16 + l15;
#pragma unroll
      for (int r = 0; r < 4; ++r) {
        int row = row0 + mi * 16 + l4 * 4 + r;
        float v = acc[mi][ni][r];
        if (ADD_BIAS) v += bias[col];
        if (OUT_BF16)
          ((unsigned short*)C)[(size_t)row * N + col] = f2bf(v);
        else
          ((float*)C)[(size_t)row * N + col] = v;
      }
    }
  }
}

// ---------------- causal flash attention, 2-phase pipelined ----------------
// grid: (SEQ/64, BATCH*NH), LPT order (qt = 31 - blockIdx.x).
// block = 256 threads = 4 waves; wave w owns 16 q-rows.
// K: global_load_lds with source pre-swizzle (linear LDS, conflict-free b128 reads).
// V: reg-staged (T14 split), scatter-transposed with swz_v = ((dh>>3)^dh)&7 (4-way writes,
//    conflict-free b128 reads). P: per-wave LDS tile, row-XOR swizzle.
__global__ __launch_bounds__(256, 2) void attn_k(const unsigned short* __restrict__ Q,
                                                 const unsigned short* __restrict__ K,
                                                 const unsigned short* __restrict__ V,
                                                 unsigned short* __restrict__ O) {
  __shared__ __align__(16) unsigned short Ks[2][64 * 128];   // 32KB dbuf
  __shared__ __align__(16) unsigned short Vt[2][128 * 64];   // 32KB dbuf, [dh][key]
  __shared__ __align__(16) unsigned short Pl[4][16 * 64];    // 8KB per-wave P

  const int tid = threadIdx.x;
  const int lane = tid & 63;
  const int l15 = lane & 15, l4 = lane >> 4;
  const int w = tid >> 6;

  const int qt = (gridDim.x - 1) - blockIdx.x;   // LPT: heavy blocks first
  const int bh = blockIdx.y;
  const int b = bh >> 4, h = bh & 15;

  const size_t base = (size_t)b * SEQ * D_MODEL + (size_t)h * DH;
  const int qw = qt * 64 + w * 16;               // first q row of this wave

  // Q fragments in registers (row = l15, k = kk*32 + l4*8 + j)
  bf16x8 qf[4];
  {
    const unsigned short* qptr = Q + base + (size_t)(qw + l15) * D_MODEL;
#pragma unroll
    for (int kk = 0; kk < 4; ++kk)
      qf[kk] = *(const bf16x8*)(qptr + kk * 32 + l4 * 8);
  }

  f32x4 acc_o[8] = {};
  float m_run[4] = {-3.4028235e38f, -3.4028235e38f, -3.4028235e38f, -3.4028235e38f};
  float lp[4] = {0.f, 0.f, 0.f, 0.f};
  const float SC = 0.12751743f;  // (1/sqrt(128)) * log2(e)

  short8 vreg[4];

  // ---- prologue: issue stage for kt=0 into buffer 0 ----
  {
    const int kv0 = 0;
#pragma unroll
    for (int it = 0; it < 4; ++it) {
      int c = tid + it * 256;
      int key = c >> 4, pos = c & 15;
      int gchunk = pos ^ (key & 7);
      const unsigned short* ga = K + base + (size_t)(kv0 + key) * D_MODEL + gchunk * 8;
      __builtin_amdgcn_global_load_lds((const __attribute__((address_space(1))) void*)ga,
                                       (__attribute__((address_space(3))) void*)(&Ks[0][c * 8]),
                                       16, 0, 0);
    }
#pragma unroll
    for (int it = 0; it < 4; ++it) {
      int c = tid + it * 256;
      int key = c >> 4, kb = c & 15;
      vreg[it] = *(const short8*)(V + base + (size_t)(kv0 + key) * D_MODEL + kb * 8);
    }
  }

  for (int kt = 0; kt <= qt; ++kt) {
    const int cur = kt & 1;
    const int kv0 = kt * 64;

    asm volatile("s_waitcnt vmcnt(0)" ::: "memory");   // K glds landed, V regs ready
    // scatter V regs -> Vt[cur] (transposed, swz_v)
#pragma unroll
    for (int it = 0; it < 4; ++it) {
      int c = tid + it * 256;
      int key = c >> 4, kb = c & 15;
      union { short8 v; unsigned short u[8]; } uv;
      uv.v = vreg[it];
#pragma unroll
      for (int j = 0; j < 8; ++j) {
        int dh = kb * 8 + j;
        int sv = ((dh >> 3) ^ dh) & 7;
        Vt[cur][dh * 64 + (key ^ (sv << 3))] = uv.u[j];
      }
    }
    __syncthreads();   // staged tile visible to all waves

    // issue next tile's stage (T3: before compute)
    if (kt < qt) {
      const int kn0 = kv0 + 64;
      const int nb = cur ^ 1;
#pragma unroll
      for (int it = 0; it < 4; ++it) {
        int c = tid + it * 256;
        int key = c >> 4, pos = c & 15;
        int gchunk = pos ^ (key & 7);
        const unsigned short* ga = K + base + (size_t)(kn0 + key) * D_MODEL + gchunk * 8;
        __builtin_amdgcn_global_load_lds((const __attribute__((address_space(1))) void*)ga,
                                         (__attribute__((address_space(3))) void*)(&Ks[nb][c * 8]),
                                         16, 0, 0);
      }
#pragma unroll
      for (int it = 0; it < 4; ++it) {
        int c = tid + it * 256;
        int key = c >> 4, kb = c & 15;
        vreg[it] = *(const short8*)(V + base + (size_t)(kn0 + key) * D_MODEL + kb * 8);
      }
    }

    // ---- S = Q K^T over current buffer ----
    f32x4 sacc[4] = {};
    __builtin_amdgcn_s_setprio(1);
#pragma unroll
    for (int st = 0; st < 4; ++st) {
      int key = st * 16 + l15;
#pragma unroll
      for (int kk = 0; kk < 4; ++kk) {
        bf16x8 kf = *(const bf16x8*)&Ks[cur][key * 128 + ((kk * 32 + l4 * 8) ^ ((key & 7) << 3))];
        sacc[st] = __builtin_amdgcn_mfma_f32_16x16x32_bf16(qf[kk], kf, sacc[st], 0, 0, 0);
      }
    }
    __builtin_amdgcn_s_setprio(0);

    // ---- online softmax ----
    float scm[4][4];
#pragma unroll
    for (int st = 0; st < 4; ++st) {
      f32x4 t = sacc[st];
      scm[st][0] = t[0]; scm[st][1] = t[1]; scm[st][2] = t[2]; scm[st][3] = t[3];
    }
    if (kt == qt) {   // diag tile only: causal mask
#pragma unroll
      for (int st = 0; st < 4; ++st)
#pragma unroll
        for (int r = 0; r < 4; ++r) {
          int key = kv0 + st * 16 + l15;
          int qr = qw + l4 * 4 + r;
          if (key > qr) scm[st][r] = -3.4028235e38f;
        }
    }
    float nm[4];
    bool grow = false;
#pragma unroll
    for (int r = 0; r < 4; ++r) {
      float t = fmaxf(fmaxf(scm[0][r], scm[1][r]), fmaxf(scm[2][r], scm[3][r]));
#pragma unroll
      for (int msk = 1; msk < 16; msk <<= 1)
        t = fmaxf(t, __shfl_xor(t, msk));
      nm[r] = fmaxf(m_run[r], t);
      grow = grow || (nm[r] > m_run[r]);
    }
    if (__any(grow)) {   // wave-uniform rescale (skipped when max stable)
#pragma unroll
      for (int r = 0; r < 4; ++r) {
        float scl = __builtin_amdgcn_exp2f((m_run[r] - nm[r]) * SC);
        m_run[r] = nm[r];
        lp[r] *= scl;
#pragma unroll
        for (int df = 0; df < 8; ++df) acc_o[df][r] *= scl;
      }
    }
    // p = exp2((s - m)*SC); lp partial (per-lane, cross-lane reduce deferred to end)
#pragma unroll
    for (int st = 0; st < 4; ++st)
#pragma unroll
      for (int r = 0; r < 4; ++r) {
        float pv = __builtin_amdgcn_exp2f((scm[st][r] - m_run[r]) * SC);
        lp[r] += pv;
        int q = l4 * 4 + r;
        int k = st * 16 + l15;
        Pl[w][q * 64 + (k ^ ((q & 7) << 3))] = f2bf(pv);
      }

    // ---- O += P V ----
    __builtin_amdgcn_s_setprio(1);
#pragma unroll
    for (int ks2 = 0; ks2 < 2; ++ks2) {
      bf16x8 pa = *(const bf16x8*)&Pl[w][l15 * 64 + ((ks2 * 32 + l4 * 8) ^ ((l15 & 7) << 3))];
#pragma unroll
      for (int df = 0; df < 8; ++df) {
        int dh = df * 16 + l15;
        int sv = ((dh >> 3) ^ dh) & 7;
        bf16x8 vb = *(const bf16x8*)&Vt[cur][dh * 64 + ((ks2 * 32 + l4 * 8) ^ (sv << 3))];
        acc_o[df] = __builtin_amdgcn_mfma_f32_16x16x32_bf16(pa, vb, acc_o[df], 0, 0, 0);
      }
    }
    __builtin_amdgcn_s_setprio(0);
  }

  // finalize: reduce partial row sums across the 16 lanes, normalize, store bf16
  float linv[4];
#pragma unroll
  for (int r = 0; r < 4; ++r) {
    float t = lp[r];
#pragma unroll
    for (int msk = 1; msk < 16; msk <<= 1)
      t += __shfl_xor(t, msk);
    linv[r] = 1.0f / t;
  }
#pragma unroll
  for (int df = 0; df < 8; ++df)
#pragma unroll
    for (int r = 0; r < 4; ++r) {
      int row = qw + l4 * 4 + r;
      O[base + (size_t)row * D_MODEL + df * 16 + l15] = f2bf(acc_o[df][r] * linv[r]);
    }
}

// ---------------- launch ----------------
extern "C" void kernel_launch(void* const* d_in, const int* in_sizes, int n_in,
                              void* d_out, int out_size, void* d_ws, size_t ws_size,
                              hipStream_t stream) {
  const float* x  = (const float*)d_in[0];
  const float* Wq = (const float*)d_in[1];
  const float* Wk = (const float*)d_in[2];
  const float* Wv = (const float*)d_in[3];
  const float* Wo = (const float*)d_in[4];
  const float* bo = (const float*)d_in[5];
  float* out = (float*)d_out;

  unsigned short* ws = (unsigned short*)d_ws;
  const size_t XSZ = (size_t)MTOT * D_MODEL;     // 16,777,216
  const size_t WSZ = (size_t)D_MODEL * D_MODEL;  // 4,194,304
  unsigned short* xb  = ws;
  unsigned short* Wqb = xb + XSZ;
  unsigned short* Wkb = Wqb + WSZ;
  unsigned short* Wvb = Wkb + WSZ;
  unsigned short* Wob = Wvb + WSZ;
  unsigned short* Qb  = Wob + WSZ;
  unsigned short* Kb  = Qb + XSZ;
  unsigned short* Vb  = Kb + XSZ;
  unsigned short* AOb = xb;   // x no longer needed after projections

  // conversions
  cvt_bf16_k<<<(int)(XSZ / 8 / 256), 256, 0, stream>>>(x, xb, (int)XSZ);
  cvt_bf16_k<<<(int)(WSZ / 8 / 256), 256, 0, stream>>>(Wq, Wqb, (int)WSZ);
  cvt_bf16_k<<<(int)(WSZ / 8 / 256), 256, 0, stream>>>(Wk, Wkb, (int)WSZ);
  cvt_bf16_k<<<(int)(WSZ / 8 / 256), 256, 0, stream>>>(Wv, Wvb, (int)WSZ);
  cvt_bf16_k<<<(int)(WSZ / 8 / 256), 256, 0, stream>>>(Wo, Wob, (int)WSZ);

  dim3 gg(MTOT / 128, D_MODEL / 128);  // 64 x 16
  gemm_bt<true, false><<<gg, 256, 0, stream>>>(xb, Wqb, Qb, nullptr, MTOT, D_MODEL, D_MODEL);
  gemm_bt<true, false><<<gg, 256, 0, stream>>>(xb, Wkb, Kb, nullptr, MTOT, D_MODEL, D_MODEL);
  gemm_bt<true, false><<<gg, 256, 0, stream>>>(xb, Wvb, Vb, nullptr, MTOT, D_MODEL, D_MODEL);

  dim3 ga(SEQ / 64, BATCH * NH);       // 32 x 64
  attn_k<<<ga, 256, 0, stream>>>(Qb, Kb, Vb, AOb);

  gemm_bt<false, true><<<gg, 256, 0, stream>>>(AOb, Wob, out, bo, MTOT, D_MODEL, D_MODEL);
}

// Round 3
// 630.751 us; speedup vs baseline: 2.5082x; 1.2185x over previous
//
#include <hip/hip_runtime.h>
#include <stdint.h>

#define D_MODEL 2048
#define NH 16
#define DH 128
#define BATCH 4
#define SEQ 2048
#define MTOT (BATCH*SEQ)   // 8192
#define LDQ 6144           // fused QKV row stride

typedef __bf16 bf16x8 __attribute__((ext_vector_type(8)));
typedef float f32x4 __attribute__((ext_vector_type(4)));
typedef short short8 __attribute__((ext_vector_type(8)));

static __device__ __forceinline__ unsigned short f2bf(float f) {
  union { float f; unsigned int u; } v; v.f = f;
  return (unsigned short)((v.u + 0x7FFFu + ((v.u >> 16) & 1u)) >> 16);
}

// ---------------- fp32 -> bf16 conversion ----------------
__global__ __launch_bounds__(256) void cvt_bf16_k(const float* __restrict__ in,
                                                  unsigned short* __restrict__ out, int n) {
  int i = (blockIdx.x * 256 + threadIdx.x) * 8;
  if (i >= n) return;
  float4 a = *(const float4*)(in + i);
  float4 b = *(const float4*)(in + i + 4);
  union { unsigned short u[8]; short8 v; } o;
  o.u[0] = f2bf(a.x); o.u[1] = f2bf(a.y); o.u[2] = f2bf(a.z); o.u[3] = f2bf(a.w);
  o.u[4] = f2bf(b.x); o.u[5] = f2bf(b.y); o.u[6] = f2bf(b.z); o.u[7] = f2bf(b.w);
  *(short8*)(out + i) = o.v;
}

// ---------------- GEMM: C[M,N] = A[M,K] * B[N,K]^T  (row-major bf16) ----------------
// 128x128 tile, BK=64, 4 waves 2x2, XCD-aware bijective swizzle (nwg % 8 == 0).
template<bool OUT_BF16, bool ADD_BIAS>
__global__ __launch_bounds__(256) void gemm_bt(const unsigned short* __restrict__ A,
                                               const unsigned short* __restrict__ B,
                                               void* __restrict__ C,
                                               const float* __restrict__ bias,
                                               int M, int N, int K) {
  __shared__ __align__(16) unsigned short As[128 * 64];
  __shared__ __align__(16) unsigned short Bs[128 * 64];
  const int tid = threadIdx.x;
  const int lane = tid & 63;
  const int l15 = lane & 15, l4 = lane >> 4;
  const int w = tid >> 6, wr = w >> 1, wc = w & 1;

  const int gx = gridDim.x;
  const int nwg = gx * gridDim.y;
  const int id = blockIdx.y * gx + blockIdx.x;
  const int cpx = nwg >> 3;
  const int swz = (id & 7) * cpx + (id >> 3);
  const int bm = swz % gx, bn = swz / gx;

  f32x4 acc[4][4] = {};

  for (int k0 = 0; k0 < K; k0 += 64) {
    __syncthreads();
#pragma unroll
    for (int it = 0; it < 4; ++it) {
      int c = tid + it * 256;
      int row = c >> 3, kb = c & 7;
      const unsigned short* ga = A + (size_t)(bm * 128 + row) * K + k0 + kb * 8;
      __builtin_amdgcn_global_load_lds((const __attribute__((address_space(1))) void*)ga,
                                       (__attribute__((address_space(3))) void*)(As + c * 8),
                                       16, 0, 0);
      const unsigned short* gb = B + (size_t)(bn * 128 + row) * K + k0 + kb * 8;
      __builtin_amdgcn_global_load_lds((const __attribute__((address_space(1))) void*)gb,
                                       (__attribute__((address_space(3))) void*)(Bs + c * 8),
                                       16, 0, 0);
    }
    asm volatile("s_waitcnt vmcnt(0)" ::: "memory");
    __syncthreads();
#pragma unroll
    for (int ks = 0; ks < 2; ++ks) {
      bf16x8 af[4], bfr[4];
#pragma unroll
      for (int mi = 0; mi < 4; ++mi)
        af[mi] = *(const bf16x8*)&As[(wr * 64 + mi * 16 + l15) * 64 + ks * 32 + l4 * 8];
#pragma unroll
      for (int ni = 0; ni < 4; ++ni)
        bfr[ni] = *(const bf16x8*)&Bs[(wc * 64 + ni * 16 + l15) * 64 + ks * 32 + l4 * 8];
#pragma unroll
      for (int mi = 0; mi < 4; ++mi)
#pragma unroll
        for (int ni = 0; ni < 4; ++ni)
          acc[mi][ni] = __builtin_amdgcn_mfma_f32_16x16x32_bf16(af[mi], bfr[ni], acc[mi][ni], 0, 0, 0);
    }
  }

  const int row0 = bm * 128 + wr * 64;
  const int col0 = bn * 128 + wc * 64;
#pragma unroll
  for (int mi = 0; mi < 4; ++mi) {
#pragma unroll
    for (int ni = 0; ni < 4; ++ni) {
      int col = col0 + ni * 16 + l15;
#pragma unroll
      for (int r = 0; r < 4; ++r) {
        int row = row0 + mi * 16 + l4 * 4 + r;
        float v = acc[mi][ni][r];
        if (ADD_BIAS) v += bias[col];
        if (OUT_BF16)
          ((unsigned short*)C)[(size_t)row * N + col] = f2bf(v);
        else
          ((float*)C)[(size_t)row * N + col] = v;
      }
    }
  }
}

// ---------------- causal flash attention ----------------
// grid (16, 64) LPT; 4 waves x QBLK=32 q-rows (128/block), KVBLK=64.
// Swapped QK^T: sacc = mfma(K, Q) -> S^T, lane l15 = its q-row. In-register row max
// (15 fmax + 2 shfl_xor), defer-max THR=8, P packed to u32 pairs -> per-wave swizzled
// LDS -> b128 A-frag reads. V reg-staged + scatter-transposed (unchanged, verified).
__global__ __launch_bounds__(256, 2) void attn_k(const unsigned short* __restrict__ Qp,
                                                 const unsigned short* __restrict__ Kp,
                                                 const unsigned short* __restrict__ Vp,
                                                 unsigned short* __restrict__ O) {
  __shared__ __align__(16) unsigned short Ks[2][64 * 128];   // 32KB dbuf
  __shared__ __align__(16) unsigned short Vt[2][128 * 64];   // 32KB dbuf, [dh][key]
  __shared__ __align__(16) unsigned int   Pl[4][32 * 32];    // 16KB: [wave][q][kw] u32

  const int tid = threadIdx.x;
  const int lane = tid & 63;
  const int l15 = lane & 15, l4 = lane >> 4;
  const int w = tid >> 6;

  const int qt = 15 - blockIdx.x;                // LPT: heavy blocks first
  const int bh = blockIdx.y;
  const int b = bh >> 4, h = bh & 15;

  const size_t baseI = (size_t)b * SEQ * LDQ + (size_t)h * DH;      // Q/K/V (stride LDQ)
  const size_t baseO = (size_t)b * SEQ * D_MODEL + (size_t)h * DH;  // O (stride 2048)
  const int qw = qt * 128 + w * 32;              // first q row of this wave

  // Q fragments (B-operand): qf[qg][kk] = Q[qw+qg*16+l15][kk*32+l4*8+j]
  bf16x8 qf[2][4];
#pragma unroll
  for (int qg = 0; qg < 2; ++qg) {
    const unsigned short* qptr = Qp + baseI + (size_t)(qw + qg * 16 + l15) * LDQ;
#pragma unroll
    for (int kk = 0; kk < 4; ++kk)
      qf[qg][kk] = *(const bf16x8*)(qptr + kk * 32 + l4 * 8);
  }

  f32x4 acc[2][8] = {};
  float m_run[2] = {-3.4028235e38f, -3.4028235e38f};
  float lp[2] = {0.f, 0.f};
  const float SC = 0.12751743f;  // (1/sqrt(128)) * log2(e)

  short8 vreg[4];
  const int nkt = 2 * qt + 2;

  // ---- prologue: stage kt=0 into buffer 0 ----
#pragma unroll
  for (int it = 0; it < 4; ++it) {
    int c = tid + it * 256;
    int key = c >> 4, pos = c & 15;
    int gchunk = pos ^ (key & 7);
    const unsigned short* ga = Kp + baseI + (size_t)key * LDQ + gchunk * 8;
    __builtin_amdgcn_global_load_lds((const __attribute__((address_space(1))) void*)ga,
                                     (__attribute__((address_space(3))) void*)(&Ks[0][c * 8]),
                                     16, 0, 0);
  }
#pragma unroll
  for (int it = 0; it < 4; ++it) {
    int c = tid + it * 256;
    int key = c >> 4, kb = c & 15;
    vreg[it] = *(const short8*)(Vp + baseI + (size_t)key * LDQ + kb * 8);
  }

  for (int kt = 0; kt < nkt; ++kt) {
    const int cur = kt & 1;
    const int kv0 = kt * 64;

    asm volatile("s_waitcnt vmcnt(0)" ::: "memory");
    // scatter V regs -> Vt[cur]
#pragma unroll
    for (int it = 0; it < 4; ++it) {
      int c = tid + it * 256;
      int key = c >> 4, kb = c & 15;
      union { short8 v; unsigned short u[8]; } uv;
      uv.v = vreg[it];
#pragma unroll
      for (int j = 0; j < 8; ++j) {
        int dh = kb * 8 + j;
        int sv = ((dh >> 3) ^ dh) & 7;
        Vt[cur][dh * 64 + (key ^ (sv << 3))] = uv.u[j];
      }
    }
    __syncthreads();

    // issue next tile's stage
    if (kt + 1 < nkt) {
      const int kn0 = kv0 + 64;
      const int nb = cur ^ 1;
#pragma unroll
      for (int it = 0; it < 4; ++it) {
        int c = tid + it * 256;
        int key = c >> 4, pos = c & 15;
        int gchunk = pos ^ (key & 7);
        const unsigned short* ga = Kp + baseI + (size_t)(kn0 + key) * LDQ + gchunk * 8;
        __builtin_amdgcn_global_load_lds((const __attribute__((address_space(1))) void*)ga,
                                         (__attribute__((address_space(3))) void*)(&Ks[nb][c * 8]),
                                         16, 0, 0);
      }
#pragma unroll
      for (int it = 0; it < 4; ++it) {
        int c = tid + it * 256;
        int key = c >> 4, kb = c & 15;
        vreg[it] = *(const short8*)(Vp + baseI + (size_t)(kn0 + key) * LDQ + kb * 8);
      }
    }

    if (kv0 <= qw + 31) {   // wave has unmasked rows in this tile
      // ---- S^T = K Q^T : sacc[qg][st], D col=l15=q, row=l4*4+r=key_local ----
      f32x4 sacc[2][4] = {};
      __builtin_amdgcn_s_setprio(1);
#pragma unroll
      for (int st = 0; st < 4; ++st) {
        int key = st * 16 + l15;
#pragma unroll
        for (int kk = 0; kk < 4; ++kk) {
          bf16x8 kf = *(const bf16x8*)&Ks[cur][key * 128 + ((kk * 32 + l4 * 8) ^ ((key & 7) << 3))];
          sacc[0][st] = __builtin_amdgcn_mfma_f32_16x16x32_bf16(kf, qf[0][kk], sacc[0][st], 0, 0, 0);
          sacc[1][st] = __builtin_amdgcn_mfma_f32_16x16x32_bf16(kf, qf[1][kk], sacc[1][st], 0, 0, 0);
        }
      }
      __builtin_amdgcn_s_setprio(0);

      const bool tail = (kv0 + 63 > qw);   // causal mask may apply
      float tmax[2];
#pragma unroll
      for (int qg = 0; qg < 2; ++qg) {
        if (tail) {
          int q = qw + qg * 16 + l15;
#pragma unroll
          for (int st = 0; st < 4; ++st)
#pragma unroll
            for (int r = 0; r < 4; ++r) {
              int key = kv0 + st * 16 + l4 * 4 + r;
              if (key > q) sacc[qg][st][r] = -3.0e38f;
            }
        }
        // in-register row max over 16 values, then reduce over l4 groups
        float a0 = fmaxf(fmaxf(sacc[qg][0][0], sacc[qg][0][1]), fmaxf(sacc[qg][0][2], sacc[qg][0][3]));
        float a1 = fmaxf(fmaxf(sacc[qg][1][0], sacc[qg][1][1]), fmaxf(sacc[qg][1][2], sacc[qg][1][3]));
        float a2 = fmaxf(fmaxf(sacc[qg][2][0], sacc[qg][2][1]), fmaxf(sacc[qg][2][2], sacc[qg][2][3]));
        float a3 = fmaxf(fmaxf(sacc[qg][3][0], sacc[qg][3][1]), fmaxf(sacc[qg][3][2], sacc[qg][3][3]));
        float t = fmaxf(fmaxf(a0, a1), fmaxf(a2, a3));
        t = fmaxf(t, __shfl_xor(t, 16));
        t = fmaxf(t, __shfl_xor(t, 32));
        tmax[qg] = t;
      }
      // defer-max: rescale only when max grows by > 8 (raw score units)
      bool grow = (tmax[0] > m_run[0] + 8.f) || (tmax[1] > m_run[1] + 8.f);
      if (__any(grow)) {
#pragma unroll
        for (int qg = 0; qg < 2; ++qg) {
          float nm = fmaxf(m_run[qg], tmax[qg]);
          float scl = __builtin_amdgcn_exp2f((m_run[qg] - nm) * SC);
          m_run[qg] = nm;
          lp[qg] *= scl;
#pragma unroll
          for (int r = 0; r < 4; ++r) {
            float srow = __shfl(scl, l4 * 4 + r);
#pragma unroll
            for (int df = 0; df < 8; ++df) acc[qg][df][r] *= srow;
          }
        }
      }
      // p = exp2((s-m)*SC); pack pairs -> per-wave swizzled LDS
#pragma unroll
      for (int qg = 0; qg < 2; ++qg) {
        int q = qg * 16 + l15;
        float ps = 0.f;
#pragma unroll
        for (int st = 0; st < 4; ++st) {
          float p0 = __builtin_amdgcn_exp2f((sacc[qg][st][0] - m_run[qg]) * SC);
          float p1 = __builtin_amdgcn_exp2f((sacc[qg][st][1] - m_run[qg]) * SC);
          float p2 = __builtin_amdgcn_exp2f((sacc[qg][st][2] - m_run[qg]) * SC);
          float p3 = __builtin_amdgcn_exp2f((sacc[qg][st][3] - m_run[qg]) * SC);
          ps += (p0 + p1) + (p2 + p3);
          unsigned w0 = (unsigned)f2bf(p0) | ((unsigned)f2bf(p1) << 16);
          unsigned w1 = (unsigned)f2bf(p2) | ((unsigned)f2bf(p3) << 16);
          int kw0 = st * 8 + l4 * 2;
          Pl[w][q * 32 + (kw0 ^ ((q & 7) << 2))] = w0;
          Pl[w][q * 32 + ((kw0 + 1) ^ ((q & 7) << 2))] = w1;
        }
        lp[qg] += ps;
      }
      // ---- O += P V : A = P (row=l15=q), B = V^T from Vt ----
      __builtin_amdgcn_s_setprio(1);
#pragma unroll
      for (int ks2 = 0; ks2 < 2; ++ks2) {
        int kwb = ks2 * 16 + l4 * 4;
        bf16x8 pa0 = *(const bf16x8*)&Pl[w][l15 * 32 + (kwb ^ ((l15 & 7) << 2))];
        bf16x8 pa1 = *(const bf16x8*)&Pl[w][(16 + l15) * 32 + (kwb ^ ((l15 & 7) << 2))];
#pragma unroll
        for (int df = 0; df < 8; ++df) {
          int dh = df * 16 + l15;
          int sv = ((dh >> 3) ^ dh) & 7;
          bf16x8 vb = *(const bf16x8*)&Vt[cur][dh * 64 + ((ks2 * 32 + l4 * 8) ^ (sv << 3))];
          acc[0][df] = __builtin_amdgcn_mfma_f32_16x16x32_bf16(pa0, vb, acc[0][df], 0, 0, 0);
          acc[1][df] = __builtin_amdgcn_mfma_f32_16x16x32_bf16(pa1, vb, acc[1][df], 0, 0, 0);
        }
      }
      __builtin_amdgcn_s_setprio(0);
    }
  }

  // finalize: reduce row sums over l4 groups, normalize, store
#pragma unroll
  for (int qg = 0; qg < 2; ++qg) {
    float t = lp[qg];
    t += __shfl_xor(t, 16);
    t += __shfl_xor(t, 32);
    float linv = 1.0f / t;
#pragma unroll
    for (int r = 0; r < 4; ++r) {
      float lrow = __shfl(linv, l4 * 4 + r);
      int row = qw + qg * 16 + l4 * 4 + r;
#pragma unroll
      for (int df = 0; df < 8; ++df)
        O[baseO + (size_t)row * D_MODEL + df * 16 + l15] = f2bf(acc[qg][df][r] * lrow);
    }
  }
}

// ---------------- launch ----------------
extern "C" void kernel_launch(void* const* d_in, const int* in_sizes, int n_in,
                              void* d_out, int out_size, void* d_ws, size_t ws_size,
                              hipStream_t stream) {
  const float* x  = (const float*)d_in[0];
  const float* Wq = (const float*)d_in[1];
  const float* Wk = (const float*)d_in[2];
  const float* Wv = (const float*)d_in[3];
  const float* Wo = (const float*)d_in[4];
  const float* bo = (const float*)d_in[5];
  float* out = (float*)d_out;

  unsigned short* ws = (unsigned short*)d_ws;
  const size_t XSZ = (size_t)MTOT * D_MODEL;      // 16,777,216
  const size_t WSZ = (size_t)D_MODEL * D_MODEL;   // 4,194,304
  unsigned short* xb   = ws;                       // also reused as attn-out
  unsigned short* Wcat = xb + XSZ;                 // [6144][2048] = Wq|Wk|Wv rows
  unsigned short* Wob  = Wcat + 3 * WSZ;
  unsigned short* QKV  = Wob + WSZ;                // [8192][6144]
  unsigned short* AOb  = xb;

  cvt_bf16_k<<<(int)(XSZ / 8 / 256), 256, 0, stream>>>(x, xb, (int)XSZ);
  cvt_bf16_k<<<(int)(WSZ / 8 / 256), 256, 0, stream>>>(Wq, Wcat, (int)WSZ);
  cvt_bf16_k<<<(int)(WSZ / 8 / 256), 256, 0, stream>>>(Wk, Wcat + WSZ, (int)WSZ);
  cvt_bf16_k<<<(int)(WSZ / 8 / 256), 256, 0, stream>>>(Wv, Wcat + 2 * WSZ, (int)WSZ);
  cvt_bf16_k<<<(int)(WSZ / 8 / 256), 256, 0, stream>>>(Wo, Wob, (int)WSZ);

  // fused QKV projection: [8192,2048] x [6144,2048]^T -> [8192,6144]
  dim3 gq(MTOT / 128, LDQ / 128);   // 64 x 48
  gemm_bt<true, false><<<gq, 256, 0, stream>>>(xb, Wcat, QKV, nullptr, MTOT, LDQ, D_MODEL);

  dim3 ga(SEQ / 128, BATCH * NH);   // 16 x 64
  attn_k<<<ga, 256, 0, stream>>>(QKV, QKV + 2048, QKV + 4096, AOb);

  dim3 gg(MTOT / 128, D_MODEL / 128);  // 64 x 16
  gemm_bt<false, true><<<gg, 256, 0, stream>>>(AOb, Wob, out, bo, MTOT, D_MODEL, D_MODEL);
}

// Round 4
// 544.000 us; speedup vs baseline: 2.9082x; 1.1595x over previous
//
#include <hip/hip_runtime.h>
#include <stdint.h>

#define D_MODEL 2048
#define NH 16
#define DH 128
#define BATCH 4
#define SEQ 2048
#define MTOT (BATCH*SEQ)   // 8192
#define LDQ 6144           // fused QKV row stride

typedef __bf16 bf16x8 __attribute__((ext_vector_type(8)));
typedef float f32x4 __attribute__((ext_vector_type(4)));
typedef short short8 __attribute__((ext_vector_type(8)));

static __device__ __forceinline__ unsigned short f2bf(float f) {
  union { float f; unsigned int u; } v; v.f = f;
  return (unsigned short)((v.u + 0x7FFFu + ((v.u >> 16) & 1u)) >> 16);
}

#define FENCEM() asm volatile("" ::: "memory")
#define GBAR() do { FENCEM(); __builtin_amdgcn_s_barrier(); FENCEM(); } while (0)

// ---------------- fp32 -> bf16 conversion ----------------
__global__ __launch_bounds__(256) void cvt_bf16_k(const float* __restrict__ in,
                                                  unsigned short* __restrict__ out, int n) {
  int i = (blockIdx.x * 256 + threadIdx.x) * 8;
  if (i >= n) return;
  float4 a = *(const float4*)(in + i);
  float4 b = *(const float4*)(in + i + 4);
  union { unsigned short u[8]; short8 v; } o;
  o.u[0] = f2bf(a.x); o.u[1] = f2bf(a.y); o.u[2] = f2bf(a.z); o.u[3] = f2bf(a.w);
  o.u[4] = f2bf(b.x); o.u[5] = f2bf(b.y); o.u[6] = f2bf(b.z); o.u[7] = f2bf(b.w);
  *(short8*)(out + i) = o.v;
}

// ---------------- 256x256 8-phase GEMM: C[M,N] = A[M,K] * B[N,K]^T ----------------
// 512 threads = 8 waves (2M x 4N); per-wave 128x64 output; BK=64; LDS 128KB dbuf.
// T2: chunk^(row&7) swizzle via pre-swizzled global source (linear glds dest).
// T3/T4: per-phase half-tile staging, counted vmcnt(4) at tile boundary only.
// T5: setprio around MFMA clusters. Raw s_barrier (no vmcnt(0) drain).
template<bool OUT_BF16, bool ADD_BIAS>
__global__ __launch_bounds__(512, 2) void gemm256(const unsigned short* __restrict__ A,
                                                  const unsigned short* __restrict__ B,
                                                  void* __restrict__ C,
                                                  const float* __restrict__ bias,
                                                  int M, int N, int K) {
  __shared__ __align__(16) unsigned short As[2][256 * 64];   // 64KB
  __shared__ __align__(16) unsigned short Bs[2][256 * 64];   // 64KB

  const int tid = threadIdx.x;
  const int lane = tid & 63;
  const int l15 = lane & 15, l4 = lane >> 4;
  const int wid = tid >> 6;
  const int wr = wid >> 2, wc = wid & 3;    // 2 x 4 wave grid

  const int gx = gridDim.x;
  const int nwg = gx * gridDim.y;
  const int id = blockIdx.y * gx + blockIdx.x;
  const int cpx = nwg >> 3;
  const int swz = (id & 7) * cpx + (id >> 3);
  const int bm = swz % gx, bn = swz / gx;

  const int NT = K >> 6;

  // staging thread constants: row st_r (0..63 per round), source chunk pre-swizzled
  const int st_r = tid >> 3;
  const int st_c = (tid & 7) ^ (st_r & 7);
  const int st_ld = st_r * 64 + (tid & 7) * 8;

#define STAGE_A(t, h) do { \
  const int _b = (t) & 1; \
  _Pragma("unroll") \
  for (int _i = 0; _i < 2; ++_i) { \
    const unsigned short* _g = A + (size_t)(bm * 256 + (h) * 128 + _i * 64 + st_r) * K + (t) * 64 + st_c * 8; \
    __builtin_amdgcn_global_load_lds((const __attribute__((address_space(1))) void*)_g, \
        (__attribute__((address_space(3))) void*)(&As[_b][(h) * 8192 + _i * 4096 + st_ld]), 16, 0, 0); \
  } \
} while (0)

#define STAGE_B(t, h) do { \
  const int _b = (t) & 1; \
  _Pragma("unroll") \
  for (int _i = 0; _i < 2; ++_i) { \
    const unsigned short* _g = B + (size_t)(bn * 256 + (h) * 128 + _i * 64 + st_r) * K + (t) * 64 + st_c * 8; \
    __builtin_amdgcn_global_load_lds((const __attribute__((address_space(1))) void*)_g, \
        (__attribute__((address_space(3))) void*)(&Bs[_b][(h) * 8192 + _i * 4096 + st_ld]), 16, 0, 0); \
  } \
} while (0)

#define LDA_F(dst, bufb, mh) do { \
  _Pragma("unroll") \
  for (int _mi = 0; _mi < 4; ++_mi) { \
    int _row = wr * 128 + (mh) * 64 + _mi * 16 + l15; \
    _Pragma("unroll") \
    for (int _kk = 0; _kk < 2; ++_kk) \
      dst[_mi][_kk] = *(const bf16x8*)&As[bufb][_row * 64 + ((_kk * 4 + l4) ^ (l15 & 7)) * 8]; \
  } \
} while (0)

#define LDB_F(dst, bufb, nq) do { \
  _Pragma("unroll") \
  for (int _ni = 0; _ni < 2; ++_ni) { \
    int _row = wc * 64 + (nq) * 32 + _ni * 16 + l15; \
    _Pragma("unroll") \
    for (int _kk = 0; _kk < 2; ++_kk) \
      dst[_ni][_kk] = *(const bf16x8*)&Bs[bufb][_row * 64 + ((_kk * 4 + l4) ^ (l15 & 7)) * 8]; \
  } \
} while (0)

#define PHASE_MFMA(MH, NQ) do { \
  __builtin_amdgcn_s_setprio(1); \
  _Pragma("unroll") \
  for (int _mi = 0; _mi < 4; ++_mi) { \
    _Pragma("unroll") \
    for (int _ni = 0; _ni < 2; ++_ni) { \
      acc[(MH) * 4 + _mi][(NQ) * 2 + _ni] = __builtin_amdgcn_mfma_f32_16x16x32_bf16( \
          af[_mi][0], bfr[_ni][0], acc[(MH) * 4 + _mi][(NQ) * 2 + _ni], 0, 0, 0); \
      acc[(MH) * 4 + _mi][(NQ) * 2 + _ni] = __builtin_amdgcn_mfma_f32_16x16x32_bf16( \
          af[_mi][1], bfr[_ni][1], acc[(MH) * 4 + _mi][(NQ) * 2 + _ni], 0, 0, 0); \
    } \
  } \
  __builtin_amdgcn_s_setprio(0); \
} while (0)

  f32x4 acc[8][4] = {};

  // ---- prologue: tile 0 full + tile 1 A halves ----
  STAGE_A(0, 0); STAGE_A(0, 1);
  STAGE_B(0, 0); STAGE_B(0, 1);
  if (NT > 1) { STAGE_A(1, 0); STAGE_A(1, 1); }
  if (NT > 1) asm volatile("s_waitcnt vmcnt(4)" ::: "memory");
  else        asm volatile("s_waitcnt vmcnt(0)" ::: "memory");
  GBAR();

  for (int t = 0; t < NT; ++t) {
    const int bufb = t & 1;
    bf16x8 af[4][2], bfr[2][2];

    // ---- phase 1: A m-half0 (8 rd) + B n-quad0 (4 rd); stage B(t+1) h0 ----
    LDA_F(af, bufb, 0);
    LDB_F(bfr, bufb, 0);
    if (t + 1 < NT) STAGE_B(t + 1, 0);
    GBAR();
    PHASE_MFMA(0, 0);
    GBAR();

    // ---- phase 2: B n-quad1 (4 rd); stage B(t+1) h1 ----
    LDB_F(bfr, bufb, 1);
    if (t + 1 < NT) STAGE_B(t + 1, 1);
    GBAR();
    PHASE_MFMA(0, 1);
    GBAR();

    // ---- phase 3: A m-half1 (8 rd) + B n-quad0 (4 rd) ----
    LDA_F(af, bufb, 1);
    LDB_F(bfr, bufb, 0);
    GBAR();
    PHASE_MFMA(1, 0);
    GBAR();

    // ---- phase 4: B n-quad1 (4 rd); stage A(t+2) both halves; boundary vmcnt ----
    LDB_F(bfr, bufb, 1);
    if (t + 2 < NT) { STAGE_A(t + 2, 0); STAGE_A(t + 2, 1); }
    GBAR();
    PHASE_MFMA(1, 1);
    if (t + 2 < NT) asm volatile("s_waitcnt vmcnt(4)" ::: "memory");
    else            asm volatile("s_waitcnt vmcnt(0)" ::: "memory");
    GBAR();
  }

  // ---- epilogue ----
  const int row0 = bm * 256 + wr * 128;
  const int col0 = bn * 256 + wc * 64;
#pragma unroll
  for (int mi = 0; mi < 8; ++mi) {
#pragma unroll
    for (int ni = 0; ni < 4; ++ni) {
      int col = col0 + ni * 16 + l15;
#pragma unroll
      for (int r = 0; r < 4; ++r) {
        int row = row0 + mi * 16 + l4 * 4 + r;
        float v = acc[mi][ni][r];
        if (ADD_BIAS) v += bias[col];
        if (OUT_BF16)
          ((unsigned short*)C)[(size_t)row * N + col] = f2bf(v);
        else
          ((float*)C)[(size_t)row * N + col] = v;
      }
    }
  }
#undef STAGE_A
#undef STAGE_B
#undef LDA_F
#undef LDB_F
#undef PHASE_MFMA
}

// ---------------- causal flash attention (unchanged, verified) ----------------
// grid (16, 64) LPT; 4 waves x QBLK=32 q-rows (128/block), KVBLK=64.
__global__ __launch_bounds__(256, 2) void attn_k(const unsigned short* __restrict__ Qp,
                                                 const unsigned short* __restrict__ Kp,
                                                 const unsigned short* __restrict__ Vp,
                                                 unsigned short* __restrict__ O) {
  __shared__ __align__(16) unsigned short Ks[2][64 * 128];
  __shared__ __align__(16) unsigned short Vt[2][128 * 64];
  __shared__ __align__(16) unsigned int   Pl[4][32 * 32];

  const int tid = threadIdx.x;
  const int lane = tid & 63;
  const int l15 = lane & 15, l4 = lane >> 4;
  const int w = tid >> 6;

  const int qt = 15 - blockIdx.x;
  const int bh = blockIdx.y;
  const int b = bh >> 4, h = bh & 15;

  const size_t baseI = (size_t)b * SEQ * LDQ + (size_t)h * DH;
  const size_t baseO = (size_t)b * SEQ * D_MODEL + (size_t)h * DH;
  const int qw = qt * 128 + w * 32;

  bf16x8 qf[2][4];
#pragma unroll
  for (int qg = 0; qg < 2; ++qg) {
    const unsigned short* qptr = Qp + baseI + (size_t)(qw + qg * 16 + l15) * LDQ;
#pragma unroll
    for (int kk = 0; kk < 4; ++kk)
      qf[qg][kk] = *(const bf16x8*)(qptr + kk * 32 + l4 * 8);
  }

  f32x4 acc[2][8] = {};
  float m_run[2] = {-3.4028235e38f, -3.4028235e38f};
  float lp[2] = {0.f, 0.f};
  const float SC = 0.12751743f;

  short8 vreg[4];
  const int nkt = 2 * qt + 2;

#pragma unroll
  for (int it = 0; it < 4; ++it) {
    int c = tid + it * 256;
    int key = c >> 4, pos = c & 15;
    int gchunk = pos ^ (key & 7);
    const unsigned short* ga = Kp + baseI + (size_t)key * LDQ + gchunk * 8;
    __builtin_amdgcn_global_load_lds((const __attribute__((address_space(1))) void*)ga,
                                     (__attribute__((address_space(3))) void*)(&Ks[0][c * 8]),
                                     16, 0, 0);
  }
#pragma unroll
  for (int it = 0; it < 4; ++it) {
    int c = tid + it * 256;
    int key = c >> 4, kb = c & 15;
    vreg[it] = *(const short8*)(Vp + baseI + (size_t)key * LDQ + kb * 8);
  }

  for (int kt = 0; kt < nkt; ++kt) {
    const int cur = kt & 1;
    const int kv0 = kt * 64;

    asm volatile("s_waitcnt vmcnt(0)" ::: "memory");
#pragma unroll
    for (int it = 0; it < 4; ++it) {
      int c = tid + it * 256;
      int key = c >> 4, kb = c & 15;
      union { short8 v; unsigned short u[8]; } uv;
      uv.v = vreg[it];
#pragma unroll
      for (int j = 0; j < 8; ++j) {
        int dh = kb * 8 + j;
        int sv = ((dh >> 3) ^ dh) & 7;
        Vt[cur][dh * 64 + (key ^ (sv << 3))] = uv.u[j];
      }
    }
    __syncthreads();

    if (kt + 1 < nkt) {
      const int kn0 = kv0 + 64;
      const int nb = cur ^ 1;
#pragma unroll
      for (int it = 0; it < 4; ++it) {
        int c = tid + it * 256;
        int key = c >> 4, pos = c & 15;
        int gchunk = pos ^ (key & 7);
        const unsigned short* ga = Kp + baseI + (size_t)(kn0 + key) * LDQ + gchunk * 8;
        __builtin_amdgcn_global_load_lds((const __attribute__((address_space(1))) void*)ga,
                                         (__attribute__((address_space(3))) void*)(&Ks[nb][c * 8]),
                                         16, 0, 0);
      }
#pragma unroll
      for (int it = 0; it < 4; ++it) {
        int c = tid + it * 256;
        int key = c >> 4, kb = c & 15;
        vreg[it] = *(const short8*)(Vp + baseI + (size_t)(kn0 + key) * LDQ + kb * 8);
      }
    }

    if (kv0 <= qw + 31) {
      f32x4 sacc[2][4] = {};
      __builtin_amdgcn_s_setprio(1);
#pragma unroll
      for (int st = 0; st < 4; ++st) {
        int key = st * 16 + l15;
#pragma unroll
        for (int kk = 0; kk < 4; ++kk) {
          bf16x8 kf = *(const bf16x8*)&Ks[cur][key * 128 + ((kk * 32 + l4 * 8) ^ ((key & 7) << 3))];
          sacc[0][st] = __builtin_amdgcn_mfma_f32_16x16x32_bf16(kf, qf[0][kk], sacc[0][st], 0, 0, 0);
          sacc[1][st] = __builtin_amdgcn_mfma_f32_16x16x32_bf16(kf, qf[1][kk], sacc[1][st], 0, 0, 0);
        }
      }
      __builtin_amdgcn_s_setprio(0);

      const bool tail = (kv0 + 63 > qw);
      float tmax[2];
#pragma unroll
      for (int qg = 0; qg < 2; ++qg) {
        if (tail) {
          int q = qw + qg * 16 + l15;
#pragma unroll
          for (int st = 0; st < 4; ++st)
#pragma unroll
            for (int r = 0; r < 4; ++r) {
              int key = kv0 + st * 16 + l4 * 4 + r;
              if (key > q) sacc[qg][st][r] = -3.0e38f;
            }
        }
        float a0 = fmaxf(fmaxf(sacc[qg][0][0], sacc[qg][0][1]), fmaxf(sacc[qg][0][2], sacc[qg][0][3]));
        float a1 = fmaxf(fmaxf(sacc[qg][1][0], sacc[qg][1][1]), fmaxf(sacc[qg][1][2], sacc[qg][1][3]));
        float a2 = fmaxf(fmaxf(sacc[qg][2][0], sacc[qg][2][1]), fmaxf(sacc[qg][2][2], sacc[qg][2][3]));
        float a3 = fmaxf(fmaxf(sacc[qg][3][0], sacc[qg][3][1]), fmaxf(sacc[qg][3][2], sacc[qg][3][3]));
        float t = fmaxf(fmaxf(a0, a1), fmaxf(a2, a3));
        t = fmaxf(t, __shfl_xor(t, 16));
        t = fmaxf(t, __shfl_xor(t, 32));
        tmax[qg] = t;
      }
      bool grow = (tmax[0] > m_run[0] + 8.f) || (tmax[1] > m_run[1] + 8.f);
      if (__any(grow)) {
#pragma unroll
        for (int qg = 0; qg < 2; ++qg) {
          float nm = fmaxf(m_run[qg], tmax[qg]);
          float scl = __builtin_amdgcn_exp2f((m_run[qg] - nm) * SC);
          m_run[qg] = nm;
          lp[qg] *= scl;
#pragma unroll
          for (int r = 0; r < 4; ++r) {
            float srow = __shfl(scl, l4 * 4 + r);
#pragma unroll
            for (int df = 0; df < 8; ++df) acc[qg][df][r] *= srow;
          }
        }
      }
#pragma unroll
      for (int qg = 0; qg < 2; ++qg) {
        int q = qg * 16 + l15;
        float ps = 0.f;
#pragma unroll
        for (int st = 0; st < 4; ++st) {
          float p0 = __builtin_amdgcn_exp2f((sacc[qg][st][0] - m_run[qg]) * SC);
          float p1 = __builtin_amdgcn_exp2f((sacc[qg][st][1] - m_run[qg]) * SC);
          float p2 = __builtin_amdgcn_exp2f((sacc[qg][st][2] - m_run[qg]) * SC);
          float p3 = __builtin_amdgcn_exp2f((sacc[qg][st][3] - m_run[qg]) * SC);
          ps += (p0 + p1) + (p2 + p3);
          unsigned w0 = (unsigned)f2bf(p0) | ((unsigned)f2bf(p1) << 16);
          unsigned w1 = (unsigned)f2bf(p2) | ((unsigned)f2bf(p3) << 16);
          int kw0 = st * 8 + l4 * 2;
          Pl[w][q * 32 + (kw0 ^ ((q & 7) << 2))] = w0;
          Pl[w][q * 32 + ((kw0 + 1) ^ ((q & 7) << 2))] = w1;
        }
        lp[qg] += ps;
      }
      __builtin_amdgcn_s_setprio(1);
#pragma unroll
      for (int ks2 = 0; ks2 < 2; ++ks2) {
        int kwb = ks2 * 16 + l4 * 4;
        bf16x8 pa0 = *(const bf16x8*)&Pl[w][l15 * 32 + (kwb ^ ((l15 & 7) << 2))];
        bf16x8 pa1 = *(const bf16x8*)&Pl[w][(16 + l15) * 32 + (kwb ^ ((l15 & 7) << 2))];
#pragma unroll
        for (int df = 0; df < 8; ++df) {
          int dh = df * 16 + l15;
          int sv = ((dh >> 3) ^ dh) & 7;
          bf16x8 vb = *(const bf16x8*)&Vt[cur][dh * 64 + ((ks2 * 32 + l4 * 8) ^ (sv << 3))];
          acc[0][df] = __builtin_amdgcn_mfma_f32_16x16x32_bf16(pa0, vb, acc[0][df], 0, 0, 0);
          acc[1][df] = __builtin_amdgcn_mfma_f32_16x16x32_bf16(pa1, vb, acc[1][df], 0, 0, 0);
        }
      }
      __builtin_amdgcn_s_setprio(0);
    }
  }

#pragma unroll
  for (int qg = 0; qg < 2; ++qg) {
    float t = lp[qg];
    t += __shfl_xor(t, 16);
    t += __shfl_xor(t, 32);
    float linv = 1.0f / t;
#pragma unroll
    for (int r = 0; r < 4; ++r) {
      float lrow = __shfl(linv, l4 * 4 + r);
      int row = qw + qg * 16 + l4 * 4 + r;
#pragma unroll
      for (int df = 0; df < 8; ++df)
        O[baseO + (size_t)row * D_MODEL + df * 16 + l15] = f2bf(acc[qg][df][r] * lrow);
    }
  }
}

// ---------------- launch ----------------
extern "C" void kernel_launch(void* const* d_in, const int* in_sizes, int n_in,
                              void* d_out, int out_size, void* d_ws, size_t ws_size,
                              hipStream_t stream) {
  const float* x  = (const float*)d_in[0];
  const float* Wq = (const float*)d_in[1];
  const float* Wk = (const float*)d_in[2];
  const float* Wv = (const float*)d_in[3];
  const float* Wo = (const float*)d_in[4];
  const float* bo = (const float*)d_in[5];
  float* out = (float*)d_out;

  unsigned short* ws = (unsigned short*)d_ws;
  const size_t XSZ = (size_t)MTOT * D_MODEL;      // 16,777,216
  const size_t WSZ = (size_t)D_MODEL * D_MODEL;   // 4,194,304
  unsigned short* xb   = ws;                       // also reused as attn-out
  unsigned short* Wcat = xb + XSZ;                 // [6144][2048] = Wq|Wk|Wv rows
  unsigned short* Wob  = Wcat + 3 * WSZ;
  unsigned short* QKV  = Wob + WSZ;                // [8192][6144]
  unsigned short* AOb  = xb;

  cvt_bf16_k<<<(int)(XSZ / 8 / 256), 256, 0, stream>>>(x, xb, (int)XSZ);
  cvt_bf16_k<<<(int)(WSZ / 8 / 256), 256, 0, stream>>>(Wq, Wcat, (int)WSZ);
  cvt_bf16_k<<<(int)(WSZ / 8 / 256), 256, 0, stream>>>(Wk, Wcat + WSZ, (int)WSZ);
  cvt_bf16_k<<<(int)(WSZ / 8 / 256), 256, 0, stream>>>(Wv, Wcat + 2 * WSZ, (int)WSZ);
  cvt_bf16_k<<<(int)(WSZ / 8 / 256), 256, 0, stream>>>(Wo, Wob, (int)WSZ);

  // fused QKV projection: [8192,2048] x [6144,2048]^T -> [8192,6144]
  dim3 gq(MTOT / 256, LDQ / 256);   // 32 x 24 = 768 blocks (%8==0)
  gemm256<true, false><<<gq, 512, 0, stream>>>(xb, Wcat, QKV, nullptr, MTOT, LDQ, D_MODEL);

  dim3 ga(SEQ / 128, BATCH * NH);   // 16 x 64
  attn_k<<<ga, 256, 0, stream>>>(QKV, QKV + 2048, QKV + 4096, AOb);

  // output projection: [8192,2048] x [2048,2048]^T -> fp32 + bias
  dim3 gg(MTOT / 256, D_MODEL / 256);  // 32 x 8 = 256 blocks (%8==0)
  gemm256<false, true><<<gg, 512, 0, stream>>>(AOb, Wob, out, bo, MTOT, D_MODEL, D_MODEL);
}

// Round 5
// 539.253 us; speedup vs baseline: 2.9338x; 1.0088x over previous
//
#include <hip/hip_runtime.h>
#include <stdint.h>

#define D_MODEL 2048
#define NH 16
#define DH 128
#define BATCH 4
#define SEQ 2048
#define MTOT (BATCH*SEQ)   // 8192
#define LDQ 6144           // fused QKV row stride

typedef __bf16 bf16x8 __attribute__((ext_vector_type(8)));
typedef float f32x4 __attribute__((ext_vector_type(4)));
typedef float f32x16 __attribute__((ext_vector_type(16)));
typedef short short8 __attribute__((ext_vector_type(8)));

static __device__ __forceinline__ unsigned short f2bf(float f) {
  union { float f; unsigned int u; } v; v.f = f;
  return (unsigned short)((v.u + 0x7FFFu + ((v.u >> 16) & 1u)) >> 16);
}

#define FENCEM() asm volatile("" ::: "memory")
#define GBAR() do { FENCEM(); __builtin_amdgcn_s_barrier(); FENCEM(); } while (0)

// ---------------- fp32 -> bf16 conversion ----------------
__global__ __launch_bounds__(256) void cvt_bf16_k(const float* __restrict__ in,
                                                  unsigned short* __restrict__ out, int n) {
  int i = (blockIdx.x * 256 + threadIdx.x) * 8;
  if (i >= n) return;
  float4 a = *(const float4*)(in + i);
  float4 b = *(const float4*)(in + i + 4);
  union { unsigned short u[8]; short8 v; } o;
  o.u[0] = f2bf(a.x); o.u[1] = f2bf(a.y); o.u[2] = f2bf(a.z); o.u[3] = f2bf(a.w);
  o.u[4] = f2bf(b.x); o.u[5] = f2bf(b.y); o.u[6] = f2bf(b.z); o.u[7] = f2bf(b.w);
  *(short8*)(out + i) = o.v;
}

// ---------------- 256x256 GEMM, 32x32x16 MFMA, read-once LDS ----------------
// 512 threads = 8 waves (2M x 4N); per-wave 128x64 out = 4m x 2n tiles of 32x32.
// BK=64; LDS 128KB dbuf; T2 chunk^(row&7) swizzle via pre-swizzled global source.
// Per K-tile: 4 phases, 24 ds_read_b128/wave (A once: 16, B once: 8; bf0/bf1 held
// in regs across phases). STAGE_A(t+2) after P3's post-MFMA barrier (WAR fence).
// Counted vmcnt(4) at tile boundary only (A(t+2) stays in flight).
template<bool OUT_BF16, bool ADD_BIAS>
__global__ __launch_bounds__(512, 2) void gemm256(const unsigned short* __restrict__ A,
                                                  const unsigned short* __restrict__ B,
                                                  void* __restrict__ C,
                                                  const float* __restrict__ bias,
                                                  int M, int N, int K) {
  __shared__ __align__(16) unsigned short As[2][256 * 64];   // 64KB
  __shared__ __align__(16) unsigned short Bs[2][256 * 64];   // 64KB

  const int tid = threadIdx.x;
  const int lane = tid & 63;
  const int l31 = lane & 31, l5 = lane >> 5;
  const int swz8 = lane & 7;
  const int wid = tid >> 6;
  const int wr = wid >> 2, wc = wid & 3;    // 2 x 4 wave grid

  const int gx = gridDim.x;
  const int nwg = gx * gridDim.y;
  const int id = blockIdx.y * gx + blockIdx.x;
  const int cpx = nwg >> 3;
  const int swz = (id & 7) * cpx + (id >> 3);
  const int bm = swz % gx, bn = swz / gx;

  const int NT = K >> 6;

  // staging: thread -> (row, pre-swizzled source chunk), linear LDS dest
  const int st_r = tid >> 3;
  const int st_c = (tid & 7) ^ (st_r & 7);
  const int st_ld = st_r * 64 + (tid & 7) * 8;

#define STAGE_A(t, h) do { \
  const int _b = (t) & 1; \
  _Pragma("unroll") \
  for (int _i = 0; _i < 2; ++_i) { \
    const unsigned short* _g = A + (size_t)(bm * 256 + (h) * 128 + _i * 64 + st_r) * K + (t) * 64 + st_c * 8; \
    __builtin_amdgcn_global_load_lds((const __attribute__((address_space(1))) void*)_g, \
        (__attribute__((address_space(3))) void*)(&As[_b][(h) * 8192 + _i * 4096 + st_ld]), 16, 0, 0); \
  } \
} while (0)

#define STAGE_B(t, h) do { \
  const int _b = (t) & 1; \
  _Pragma("unroll") \
  for (int _i = 0; _i < 2; ++_i) { \
    const unsigned short* _g = B + (size_t)(bn * 256 + (h) * 128 + _i * 64 + st_r) * K + (t) * 64 + st_c * 8; \
    __builtin_amdgcn_global_load_lds((const __attribute__((address_space(1))) void*)_g, \
        (__attribute__((address_space(3))) void*)(&Bs[_b][(h) * 8192 + _i * 4096 + st_ld]), 16, 0, 0); \
  } \
} while (0)

// A-frags for m-half mh (2 tiles of 32x32, all 4 k-slots): row=lane&31, k=l5*8+j
#define LDA32(mh) do { \
  _Pragma("unroll") \
  for (int _mt = 0; _mt < 2; ++_mt) { \
    int _row = wr * 128 + ((mh) * 2 + _mt) * 32 + l31; \
    _Pragma("unroll") \
    for (int _ks = 0; _ks < 4; ++_ks) \
      af[_mt][_ks] = *(const bf16x8*)&As[bufb][_row * 64 + (((_ks * 2 + l5) ^ swz8) * 8)]; \
  } \
} while (0)

// B-frags for n-tile nq (all 4 k-slots)
#define LDB32(nq, dst) do { \
  int _row = wc * 64 + (nq) * 32 + l31; \
  _Pragma("unroll") \
  for (int _ks = 0; _ks < 4; ++_ks) \
    dst[_ks] = *(const bf16x8*)&Bs[bufb][_row * 64 + (((_ks * 2 + l5) ^ swz8) * 8)]; \
} while (0)

#define PH_MFMA(mh, nq, bfr) do { \
  __builtin_amdgcn_s_setprio(1); \
  _Pragma("unroll") \
  for (int _ks = 0; _ks < 4; ++_ks) { \
    _Pragma("unroll") \
    for (int _mt = 0; _mt < 2; ++_mt) \
      acc[(mh) * 2 + _mt][nq] = __builtin_amdgcn_mfma_f32_32x32x16_bf16( \
          af[_mt][_ks], bfr[_ks], acc[(mh) * 2 + _mt][nq], 0, 0, 0); \
  } \
  __builtin_amdgcn_s_setprio(0); \
} while (0)

  f32x16 acc[4][2] = {};

  // ---- prologue: tile 0 full + tile 1 A halves ----
  STAGE_A(0, 0); STAGE_A(0, 1);
  STAGE_B(0, 0); STAGE_B(0, 1);
  if (NT > 1) { STAGE_A(1, 0); STAGE_A(1, 1); }
  if (NT > 1) asm volatile("s_waitcnt vmcnt(4)" ::: "memory");
  else        asm volatile("s_waitcnt vmcnt(0)" ::: "memory");
  GBAR();

  for (int t = 0; t < NT; ++t) {
    const int bufb = t & 1;
    bf16x8 af[2][4], bf0[4], bf1[4];

    // ---- phase 1: LD A(m01) 8rd + B(n0) 4rd; stage B(t+1)h0 ----
    LDA32(0);
    LDB32(0, bf0);
    if (t + 1 < NT) STAGE_B(t + 1, 0);
    GBAR();
    PH_MFMA(0, 0, bf0);
    GBAR();

    // ---- phase 2: LD B(n1) 4rd; stage B(t+1)h1 ----
    LDB32(1, bf1);
    if (t + 1 < NT) STAGE_B(t + 1, 1);
    GBAR();
    PH_MFMA(0, 1, bf1);
    GBAR();

    // ---- phase 3: LD A(m23) 8rd ----
    LDA32(1);
    GBAR();
    PH_MFMA(1, 1, bf1);
    GBAR();   // WAR fence: all waves' A-reads done before A(t+2) stage below

    // ---- phase 4: no ds_read; stage A(t+2); MFMA; boundary vmcnt ----
    if (t + 2 < NT) { STAGE_A(t + 2, 0); STAGE_A(t + 2, 1); }
    PH_MFMA(1, 0, bf0);
    if (t + 2 < NT) asm volatile("s_waitcnt vmcnt(4)" ::: "memory");
    else            asm volatile("s_waitcnt vmcnt(0)" ::: "memory");
    GBAR();
  }

  // ---- epilogue: C/D layout col=lane&31, row=(reg&3)+8*(reg>>2)+4*(lane>>5) ----
  const int row0 = bm * 256 + wr * 128;
  const int col0 = bn * 256 + wc * 64;
#pragma unroll
  for (int mi = 0; mi < 4; ++mi) {
#pragma unroll
    for (int ni = 0; ni < 2; ++ni) {
      int col = col0 + ni * 32 + l31;
      float bv = ADD_BIAS ? bias[col] : 0.f;
#pragma unroll
      for (int g = 0; g < 4; ++g) {
#pragma unroll
        for (int q = 0; q < 4; ++q) {
          int row = row0 + mi * 32 + q + g * 8 + l5 * 4;
          float v = acc[mi][ni][g * 4 + q];
          if (ADD_BIAS) v += bv;
          if (OUT_BF16)
            ((unsigned short*)C)[(size_t)row * N + col] = f2bf(v);
          else
            ((float*)C)[(size_t)row * N + col] = v;
        }
      }
    }
  }
#undef STAGE_A
#undef STAGE_B
#undef LDA32
#undef LDB32
#undef PH_MFMA
}

// ---------------- causal flash attention (unchanged, verified) ----------------
// grid (16, 64) LPT; 4 waves x QBLK=32 q-rows (128/block), KVBLK=64.
__global__ __launch_bounds__(256, 2) void attn_k(const unsigned short* __restrict__ Qp,
                                                 const unsigned short* __restrict__ Kp,
                                                 const unsigned short* __restrict__ Vp,
                                                 unsigned short* __restrict__ O) {
  __shared__ __align__(16) unsigned short Ks[2][64 * 128];
  __shared__ __align__(16) unsigned short Vt[2][128 * 64];
  __shared__ __align__(16) unsigned int   Pl[4][32 * 32];

  const int tid = threadIdx.x;
  const int lane = tid & 63;
  const int l15 = lane & 15, l4 = lane >> 4;
  const int w = tid >> 6;

  const int qt = 15 - blockIdx.x;
  const int bh = blockIdx.y;
  const int b = bh >> 4, h = bh & 15;

  const size_t baseI = (size_t)b * SEQ * LDQ + (size_t)h * DH;
  const size_t baseO = (size_t)b * SEQ * D_MODEL + (size_t)h * DH;
  const int qw = qt * 128 + w * 32;

  bf16x8 qf[2][4];
#pragma unroll
  for (int qg = 0; qg < 2; ++qg) {
    const unsigned short* qptr = Qp + baseI + (size_t)(qw + qg * 16 + l15) * LDQ;
#pragma unroll
    for (int kk = 0; kk < 4; ++kk)
      qf[qg][kk] = *(const bf16x8*)(qptr + kk * 32 + l4 * 8);
  }

  f32x4 acc[2][8] = {};
  float m_run[2] = {-3.4028235e38f, -3.4028235e38f};
  float lp[2] = {0.f, 0.f};
  const float SC = 0.12751743f;

  short8 vreg[4];
  const int nkt = 2 * qt + 2;

#pragma unroll
  for (int it = 0; it < 4; ++it) {
    int c = tid + it * 256;
    int key = c >> 4, pos = c & 15;
    int gchunk = pos ^ (key & 7);
    const unsigned short* ga = Kp + baseI + (size_t)key * LDQ + gchunk * 8;
    __builtin_amdgcn_global_load_lds((const __attribute__((address_space(1))) void*)ga,
                                     (__attribute__((address_space(3))) void*)(&Ks[0][c * 8]),
                                     16, 0, 0);
  }
#pragma unroll
  for (int it = 0; it < 4; ++it) {
    int c = tid + it * 256;
    int key = c >> 4, kb = c & 15;
    vreg[it] = *(const short8*)(Vp + baseI + (size_t)key * LDQ + kb * 8);
  }

  for (int kt = 0; kt < nkt; ++kt) {
    const int cur = kt & 1;
    const int kv0 = kt * 64;

    asm volatile("s_waitcnt vmcnt(0)" ::: "memory");
#pragma unroll
    for (int it = 0; it < 4; ++it) {
      int c = tid + it * 256;
      int key = c >> 4, kb = c & 15;
      union { short8 v; unsigned short u[8]; } uv;
      uv.v = vreg[it];
#pragma unroll
      for (int j = 0; j < 8; ++j) {
        int dh = kb * 8 + j;
        int sv = ((dh >> 3) ^ dh) & 7;
        Vt[cur][dh * 64 + (key ^ (sv << 3))] = uv.u[j];
      }
    }
    __syncthreads();

    if (kt + 1 < nkt) {
      const int kn0 = kv0 + 64;
      const int nb = cur ^ 1;
#pragma unroll
      for (int it = 0; it < 4; ++it) {
        int c = tid + it * 256;
        int key = c >> 4, pos = c & 15;
        int gchunk = pos ^ (key & 7);
        const unsigned short* ga = Kp + baseI + (size_t)(kn0 + key) * LDQ + gchunk * 8;
        __builtin_amdgcn_global_load_lds((const __attribute__((address_space(1))) void*)ga,
                                         (__attribute__((address_space(3))) void*)(&Ks[nb][c * 8]),
                                         16, 0, 0);
      }
#pragma unroll
      for (int it = 0; it < 4; ++it) {
        int c = tid + it * 256;
        int key = c >> 4, kb = c & 15;
        vreg[it] = *(const short8*)(Vp + baseI + (size_t)(kn0 + key) * LDQ + kb * 8);
      }
    }

    if (kv0 <= qw + 31) {
      f32x4 sacc[2][4] = {};
      __builtin_amdgcn_s_setprio(1);
#pragma unroll
      for (int st = 0; st < 4; ++st) {
        int key = st * 16 + l15;
#pragma unroll
        for (int kk = 0; kk < 4; ++kk) {
          bf16x8 kf = *(const bf16x8*)&Ks[cur][key * 128 + ((kk * 32 + l4 * 8) ^ ((key & 7) << 3))];
          sacc[0][st] = __builtin_amdgcn_mfma_f32_16x16x32_bf16(kf, qf[0][kk], sacc[0][st], 0, 0, 0);
          sacc[1][st] = __builtin_amdgcn_mfma_f32_16x16x32_bf16(kf, qf[1][kk], sacc[1][st], 0, 0, 0);
        }
      }
      __builtin_amdgcn_s_setprio(0);

      const bool tail = (kv0 + 63 > qw);
      float tmax[2];
#pragma unroll
      for (int qg = 0; qg < 2; ++qg) {
        if (tail) {
          int q = qw + qg * 16 + l15;
#pragma unroll
          for (int st = 0; st < 4; ++st)
#pragma unroll
            for (int r = 0; r < 4; ++r) {
              int key = kv0 + st * 16 + l4 * 4 + r;
              if (key > q) sacc[qg][st][r] = -3.0e38f;
            }
        }
        float a0 = fmaxf(fmaxf(sacc[qg][0][0], sacc[qg][0][1]), fmaxf(sacc[qg][0][2], sacc[qg][0][3]));
        float a1 = fmaxf(fmaxf(sacc[qg][1][0], sacc[qg][1][1]), fmaxf(sacc[qg][1][2], sacc[qg][1][3]));
        float a2 = fmaxf(fmaxf(sacc[qg][2][0], sacc[qg][2][1]), fmaxf(sacc[qg][2][2], sacc[qg][2][3]));
        float a3 = fmaxf(fmaxf(sacc[qg][3][0], sacc[qg][3][1]), fmaxf(sacc[qg][3][2], sacc[qg][3][3]));
        float t = fmaxf(fmaxf(a0, a1), fmaxf(a2, a3));
        t = fmaxf(t, __shfl_xor(t, 16));
        t = fmaxf(t, __shfl_xor(t, 32));
        tmax[qg] = t;
      }
      bool grow = (tmax[0] > m_run[0] + 8.f) || (tmax[1] > m_run[1] + 8.f);
      if (__any(grow)) {
#pragma unroll
        for (int qg = 0; qg < 2; ++qg) {
          float nm = fmaxf(m_run[qg], tmax[qg]);
          float scl = __builtin_amdgcn_exp2f((m_run[qg] - nm) * SC);
          m_run[qg] = nm;
          lp[qg] *= scl;
#pragma unroll
          for (int r = 0; r < 4; ++r) {
            float srow = __shfl(scl, l4 * 4 + r);
#pragma unroll
            for (int df = 0; df < 8; ++df) acc[qg][df][r] *= srow;
          }
        }
      }
#pragma unroll
      for (int qg = 0; qg < 2; ++qg) {
        int q = qg * 16 + l15;
        float ps = 0.f;
#pragma unroll
        for (int st = 0; st < 4; ++st) {
          float p0 = __builtin_amdgcn_exp2f((sacc[qg][st][0] - m_run[qg]) * SC);
          float p1 = __builtin_amdgcn_exp2f((sacc[qg][st][1] - m_run[qg]) * SC);
          float p2 = __builtin_amdgcn_exp2f((sacc[qg][st][2] - m_run[qg]) * SC);
          float p3 = __builtin_amdgcn_exp2f((sacc[qg][st][3] - m_run[qg]) * SC);
          ps += (p0 + p1) + (p2 + p3);
          unsigned w0 = (unsigned)f2bf(p0) | ((unsigned)f2bf(p1) << 16);
          unsigned w1 = (unsigned)f2bf(p2) | ((unsigned)f2bf(p3) << 16);
          int kw0 = st * 8 + l4 * 2;
          Pl[w][q * 32 + (kw0 ^ ((q & 7) << 2))] = w0;
          Pl[w][q * 32 + ((kw0 + 1) ^ ((q & 7) << 2))] = w1;
        }
        lp[qg] += ps;
      }
      __builtin_amdgcn_s_setprio(1);
#pragma unroll
      for (int ks2 = 0; ks2 < 2; ++ks2) {
        int kwb = ks2 * 16 + l4 * 4;
        bf16x8 pa0 = *(const bf16x8*)&Pl[w][l15 * 32 + (kwb ^ ((l15 & 7) << 2))];
        bf16x8 pa1 = *(const bf16x8*)&Pl[w][(16 + l15) * 32 + (kwb ^ ((l15 & 7) << 2))];
#pragma unroll
        for (int df = 0; df < 8; ++df) {
          int dh = df * 16 + l15;
          int sv = ((dh >> 3) ^ dh) & 7;
          bf16x8 vb = *(const bf16x8*)&Vt[cur][dh * 64 + ((ks2 * 32 + l4 * 8) ^ (sv << 3))];
          acc[0][df] = __builtin_amdgcn_mfma_f32_16x16x32_bf16(pa0, vb, acc[0][df], 0, 0, 0);
          acc[1][df] = __builtin_amdgcn_mfma_f32_16x16x32_bf16(pa1, vb, acc[1][df], 0, 0, 0);
        }
      }
      __builtin_amdgcn_s_setprio(0);
    }
  }

#pragma unroll
  for (int qg = 0; qg < 2; ++qg) {
    float t = lp[qg];
    t += __shfl_xor(t, 16);
    t += __shfl_xor(t, 32);
    float linv = 1.0f / t;
#pragma unroll
    for (int r = 0; r < 4; ++r) {
      float lrow = __shfl(linv, l4 * 4 + r);
      int row = qw + qg * 16 + l4 * 4 + r;
#pragma unroll
      for (int df = 0; df < 8; ++df)
        O[baseO + (size_t)row * D_MODEL + df * 16 + l15] = f2bf(acc[qg][df][r] * lrow);
    }
  }
}

// ---------------- launch ----------------
extern "C" void kernel_launch(void* const* d_in, const int* in_sizes, int n_in,
                              void* d_out, int out_size, void* d_ws, size_t ws_size,
                              hipStream_t stream) {
  const float* x  = (const float*)d_in[0];
  const float* Wq = (const float*)d_in[1];
  const float* Wk = (const float*)d_in[2];
  const float* Wv = (const float*)d_in[3];
  const float* Wo = (const float*)d_in[4];
  const float* bo = (const float*)d_in[5];
  float* out = (float*)d_out;

  unsigned short* ws = (unsigned short*)d_ws;
  const size_t XSZ = (size_t)MTOT * D_MODEL;      // 16,777,216
  const size_t WSZ = (size_t)D_MODEL * D_MODEL;   // 4,194,304
  unsigned short* xb   = ws;                       // also reused as attn-out
  unsigned short* Wcat = xb + XSZ;                 // [6144][2048] = Wq|Wk|Wv rows
  unsigned short* Wob  = Wcat + 3 * WSZ;
  unsigned short* QKV  = Wob + WSZ;                // [8192][6144]
  unsigned short* AOb  = xb;

  cvt_bf16_k<<<(int)(XSZ / 8 / 256), 256, 0, stream>>>(x, xb, (int)XSZ);
  cvt_bf16_k<<<(int)(WSZ / 8 / 256), 256, 0, stream>>>(Wq, Wcat, (int)WSZ);
  cvt_bf16_k<<<(int)(WSZ / 8 / 256), 256, 0, stream>>>(Wk, Wcat + WSZ, (int)WSZ);
  cvt_bf16_k<<<(int)(WSZ / 8 / 256), 256, 0, stream>>>(Wv, Wcat + 2 * WSZ, (int)WSZ);
  cvt_bf16_k<<<(int)(WSZ / 8 / 256), 256, 0, stream>>>(Wo, Wob, (int)WSZ);

  // fused QKV projection: [8192,2048] x [6144,2048]^T -> [8192,6144]
  dim3 gq(MTOT / 256, LDQ / 256);   // 32 x 24 = 768 blocks (%8==0)
  gemm256<true, false><<<gq, 512, 0, stream>>>(xb, Wcat, QKV, nullptr, MTOT, LDQ, D_MODEL);

  dim3 ga(SEQ / 128, BATCH * NH);   // 16 x 64
  attn_k<<<ga, 256, 0, stream>>>(QKV, QKV + 2048, QKV + 4096, AOb);

  // output projection: [8192,2048] x [2048,2048]^T -> fp32 + bias
  dim3 gg(MTOT / 256, D_MODEL / 256);  // 32 x 8 = 256 blocks (%8==0)
  gemm256<false, true><<<gg, 512, 0, stream>>>(AOb, Wob, out, bo, MTOT, D_MODEL, D_MODEL);
}

// Round 7
// 534.777 us; speedup vs baseline: 2.9584x; 1.0084x over previous
//
#include <hip/hip_runtime.h>
#include <stdint.h>

#define D_MODEL 2048
#define NH 16
#define DH 128
#define BATCH 4
#define SEQ 2048
#define MTOT (BATCH*SEQ)   // 8192
#define LDQ 6144           // fused QKV row stride

typedef __bf16 bf16x8 __attribute__((ext_vector_type(8)));
typedef float f32x4 __attribute__((ext_vector_type(4)));
typedef short short8 __attribute__((ext_vector_type(8)));

static __device__ __forceinline__ unsigned short f2bf(float f) {
  union { float f; unsigned int u; } v; v.f = f;
  return (unsigned short)((v.u + 0x7FFFu + ((v.u >> 16) & 1u)) >> 16);
}

#define FENCEM() asm volatile("" ::: "memory")
#define GBAR() do { FENCEM(); __builtin_amdgcn_s_barrier(); FENCEM(); } while (0)

// ---------------- fp32 -> bf16 conversion ----------------
__global__ __launch_bounds__(256) void cvt_bf16_k(const float* __restrict__ in,
                                                  unsigned short* __restrict__ out, int n) {
  int i = (blockIdx.x * 256 + threadIdx.x) * 8;
  if (i >= n) return;
  float4 a = *(const float4*)(in + i);
  float4 b = *(const float4*)(in + i + 4);
  union { unsigned short u[8]; short8 v; } o;
  o.u[0] = f2bf(a.x); o.u[1] = f2bf(a.y); o.u[2] = f2bf(a.z); o.u[3] = f2bf(a.w);
  o.u[4] = f2bf(b.x); o.u[5] = f2bf(b.y); o.u[6] = f2bf(b.z); o.u[7] = f2bf(b.w);
  *(short8*)(out + i) = o.v;
}

// 4 weight tensors in one dispatch (blockIdx.y selects slice)
__global__ __launch_bounds__(256) void cvt_w_k(const float* __restrict__ w0, const float* __restrict__ w1,
                                               const float* __restrict__ w2, const float* __restrict__ w3,
                                               unsigned short* __restrict__ o0, unsigned short* __restrict__ o1,
                                               unsigned short* __restrict__ o2, unsigned short* __restrict__ o3) {
  const float* src; unsigned short* dst;
  switch (blockIdx.y) {
    case 0: src = w0; dst = o0; break;
    case 1: src = w1; dst = o1; break;
    case 2: src = w2; dst = o2; break;
    default: src = w3; dst = o3; break;
  }
  int i = (blockIdx.x * 256 + threadIdx.x) * 8;
  float4 a = *(const float4*)(src + i);
  float4 b = *(const float4*)(src + i + 4);
  union { unsigned short u[8]; short8 v; } o;
  o.u[0] = f2bf(a.x); o.u[1] = f2bf(a.y); o.u[2] = f2bf(a.z); o.u[3] = f2bf(a.w);
  o.u[4] = f2bf(b.x); o.u[5] = f2bf(b.y); o.u[6] = f2bf(b.z); o.u[7] = f2bf(b.w);
  *(short8*)(dst + i) = o.v;
}

// ---------------- 256x256 8-phase GEMM, B-fragments held across phases ----------------
// 512 threads = 8 waves (2M x 4N); per-wave 128x64; BK=64; LDS 128KB dbuf.
// Read patterns identical to round-4 verified (0 conflicts); B read ONCE per K-tile
// (bf0/bf1 live in regs), A once: 24 ds_read_b128/wave/K-tile (was 32).
// Staging/vmcnt protocol identical to round-4 verified proof.
template<bool OUT_BF16, bool ADD_BIAS>
__global__ __launch_bounds__(512, 2) void gemm256(const unsigned short* __restrict__ A,
                                                  const unsigned short* __restrict__ B,
                                                  void* __restrict__ C,
                                                  const float* __restrict__ bias,
                                                  int M, int N, int K) {
  __shared__ __align__(16) unsigned short As[2][256 * 64];   // 64KB
  __shared__ __align__(16) unsigned short Bs[2][256 * 64];   // 64KB

  const int tid = threadIdx.x;
  const int lane = tid & 63;
  const int l15 = lane & 15, l4 = lane >> 4;
  const int wid = tid >> 6;
  const int wr = wid >> 2, wc = wid & 3;    // 2 x 4 wave grid

  const int gx = gridDim.x;
  const int nwg = gx * gridDim.y;
  const int id = blockIdx.y * gx + blockIdx.x;
  const int cpx = nwg >> 3;
  const int swz = (id & 7) * cpx + (id >> 3);
  const int bm = swz % gx, bn = swz / gx;

  const int NT = K >> 6;

  const int st_r = tid >> 3;
  const int st_c = (tid & 7) ^ (st_r & 7);
  const int st_ld = st_r * 64 + (tid & 7) * 8;

#define STAGE_A(t, h) do { \
  const int _b = (t) & 1; \
  _Pragma("unroll") \
  for (int _i = 0; _i < 2; ++_i) { \
    const unsigned short* _g = A + (size_t)(bm * 256 + (h) * 128 + _i * 64 + st_r) * K + (t) * 64 + st_c * 8; \
    __builtin_amdgcn_global_load_lds((const __attribute__((address_space(1))) void*)_g, \
        (__attribute__((address_space(3))) void*)(&As[_b][(h) * 8192 + _i * 4096 + st_ld]), 16, 0, 0); \
  } \
} while (0)

#define STAGE_B(t, h) do { \
  const int _b = (t) & 1; \
  _Pragma("unroll") \
  for (int _i = 0; _i < 2; ++_i) { \
    const unsigned short* _g = B + (size_t)(bn * 256 + (h) * 128 + _i * 64 + st_r) * K + (t) * 64 + st_c * 8; \
    __builtin_amdgcn_global_load_lds((const __attribute__((address_space(1))) void*)_g, \
        (__attribute__((address_space(3))) void*)(&Bs[_b][(h) * 8192 + _i * 4096 + st_ld]), 16, 0, 0); \
  } \
} while (0)

#define LDA_F(dst, bufb, mh) do { \
  _Pragma("unroll") \
  for (int _mi = 0; _mi < 4; ++_mi) { \
    int _row = wr * 128 + (mh) * 64 + _mi * 16 + l15; \
    _Pragma("unroll") \
    for (int _kk = 0; _kk < 2; ++_kk) \
      dst[_mi][_kk] = *(const bf16x8*)&As[bufb][_row * 64 + ((_kk * 4 + l4) ^ (l15 & 7)) * 8]; \
  } \
} while (0)

#define LDB_F(dst, bufb, nq) do { \
  _Pragma("unroll") \
  for (int _ni = 0; _ni < 2; ++_ni) { \
    int _row = wc * 64 + (nq) * 32 + _ni * 16 + l15; \
    _Pragma("unroll") \
    for (int _kk = 0; _kk < 2; ++_kk) \
      dst[_ni][_kk] = *(const bf16x8*)&Bs[bufb][_row * 64 + ((_kk * 4 + l4) ^ (l15 & 7)) * 8]; \
  } \
} while (0)

#define PHASE_MFMA(MH, NQ, BFR) do { \
  __builtin_amdgcn_s_setprio(1); \
  _Pragma("unroll") \
  for (int _mi = 0; _mi < 4; ++_mi) { \
    _Pragma("unroll") \
    for (int _ni = 0; _ni < 2; ++_ni) { \
      acc[(MH) * 4 + _mi][(NQ) * 2 + _ni] = __builtin_amdgcn_mfma_f32_16x16x32_bf16( \
          af[_mi][0], BFR[_ni][0], acc[(MH) * 4 + _mi][(NQ) * 2 + _ni], 0, 0, 0); \
      acc[(MH) * 4 + _mi][(NQ) * 2 + _ni] = __builtin_amdgcn_mfma_f32_16x16x32_bf16( \
          af[_mi][1], BFR[_ni][1], acc[(MH) * 4 + _mi][(NQ) * 2 + _ni], 0, 0, 0); \
    } \
  } \
  __builtin_amdgcn_s_setprio(0); \
} while (0)

  f32x4 acc[8][4] = {};

  STAGE_A(0, 0); STAGE_A(0, 1);
  STAGE_B(0, 0); STAGE_B(0, 1);
  if (NT > 1) { STAGE_A(1, 0); STAGE_A(1, 1); }
  if (NT > 1) asm volatile("s_waitcnt vmcnt(4)" ::: "memory");
  else        asm volatile("s_waitcnt vmcnt(0)" ::: "memory");
  GBAR();

  for (int t = 0; t < NT; ++t) {
    const int bufb = t & 1;
    bf16x8 af[4][2], bf0[2][2], bf1[2][2];

    // ---- P1: LDA(h0) 8rd + LDB(bf0,n0) 4rd; stage B(t+1)h0 ----
    LDA_F(af, bufb, 0);
    LDB_F(bf0, bufb, 0);
    if (t + 1 < NT) STAGE_B(t + 1, 0);
    GBAR();
    PHASE_MFMA(0, 0, bf0);
    GBAR();

    // ---- P2: LDB(bf1,n1) 4rd; stage B(t+1)h1 ----
    LDB_F(bf1, bufb, 1);
    if (t + 1 < NT) STAGE_B(t + 1, 1);
    GBAR();
    PHASE_MFMA(0, 1, bf1);
    GBAR();

    // ---- P3: LDA(h1) 8rd ----
    LDA_F(af, bufb, 1);
    GBAR();
    PHASE_MFMA(1, 1, bf1);
    GBAR();   // WAR fence: all A/B reads of tile t complete before A(t+2) staging

    // ---- P4: no ds_reads; stage A(t+2); MFMA(1,0); boundary vmcnt ----
    if (t + 2 < NT) { STAGE_A(t + 2, 0); STAGE_A(t + 2, 1); }
    PHASE_MFMA(1, 0, bf0);
    if (t + 2 < NT) asm volatile("s_waitcnt vmcnt(4)" ::: "memory");
    else            asm volatile("s_waitcnt vmcnt(0)" ::: "memory");
    GBAR();
  }

  const int row0 = bm * 256 + wr * 128;
  const int col0 = bn * 256 + wc * 64;
#pragma unroll
  for (int mi = 0; mi < 8; ++mi) {
#pragma unroll
    for (int ni = 0; ni < 4; ++ni) {
      int col = col0 + ni * 16 + l15;
#pragma unroll
      for (int r = 0; r < 4; ++r) {
        int row = row0 + mi * 16 + l4 * 4 + r;
        float v = acc[mi][ni][r];
        if (ADD_BIAS) v += bias[col];
        if (OUT_BF16)
          ((unsigned short*)C)[(size_t)row * N + col] = f2bf(v);
        else
          ((float*)C)[(size_t)row * N + col] = v;
      }
    }
  }
#undef STAGE_A
#undef STAGE_B
#undef LDA_F
#undef LDB_F
#undef PHASE_MFMA
}

// ---------------- causal flash attention (round-5 verified structure) ----------------
// grid (16, 64) LPT; 4 waves x QBLK=32 q-rows (128/block), KVBLK=64.
// K: glds with chunk^(key&7) source swizzle (linear LDS dest, conflict-free b128 reads).
// V: reg-staged, PAIRED scatter-transpose — thread loads keys {2kp,2kp+1} same dh-chunk,
//    writes ds_write_b32 pairs; same LDS image as verified (sv=(ch^j)&7 == ((dh>>3)^dh)&7),
//    16 b32 writes/thread (was 32 b16), 2-way bank spread (free).
__global__ __launch_bounds__(256, 2) void attn_k(const unsigned short* __restrict__ Qp,
                                                 const unsigned short* __restrict__ Kp,
                                                 const unsigned short* __restrict__ Vp,
                                                 unsigned short* __restrict__ O) {
  __shared__ __align__(16) unsigned short Ks[2][64 * 128];   // 32KB dbuf
  __shared__ __align__(16) unsigned short Vt[2][128 * 64];   // 32KB dbuf, [dh][key]
  __shared__ __align__(16) unsigned int   Pl[4][32 * 32];    // 16KB per-wave P

  const int tid = threadIdx.x;
  const int lane = tid & 63;
  const int l15 = lane & 15, l4 = lane >> 4;
  const int w = tid >> 6;

  const int qt = 15 - blockIdx.x;                // LPT: heavy blocks first
  const int bh = blockIdx.y;
  const int b = bh >> 4, h = bh & 15;

  const size_t baseI = (size_t)b * SEQ * LDQ + (size_t)h * DH;
  const size_t baseO = (size_t)b * SEQ * D_MODEL + (size_t)h * DH;
  const int qw = qt * 128 + w * 32;

  bf16x8 qf[2][4];
#pragma unroll
  for (int qg = 0; qg < 2; ++qg) {
    const unsigned short* qptr = Qp + baseI + (size_t)(qw + qg * 16 + l15) * LDQ;
#pragma unroll
    for (int kk = 0; kk < 4; ++kk)
      qf[qg][kk] = *(const bf16x8*)(qptr + kk * 32 + l4 * 8);
  }

  f32x4 acc[2][8] = {};
  float m_run[2] = {-3.4028235e38f, -3.4028235e38f};
  float lp[2] = {0.f, 0.f};
  const float SC = 0.12751743f;  // (1/sqrt(128)) * log2(e)

  short8 vreg[4];
  const int nkt = 2 * qt + 2;

  // thread constants for V pairing: kp = key-pair index, ch = dh chunk
  const int vkp0 = tid >> 4, vch0 = tid & 15;          // c = tid
  const int vkp1 = (tid + 256) >> 4, vch1 = vch0;      // c = tid + 256

  // ---- prologue: stage kt=0 ----
#pragma unroll
  for (int it = 0; it < 4; ++it) {
    int c = tid + it * 256;
    int key = c >> 4, pos = c & 15;
    int gchunk = pos ^ (key & 7);
    const unsigned short* ga = Kp + baseI + (size_t)key * LDQ + gchunk * 8;
    __builtin_amdgcn_global_load_lds((const __attribute__((address_space(1))) void*)ga,
                                     (__attribute__((address_space(3))) void*)(&Ks[0][c * 8]),
                                     16, 0, 0);
  }
  {
    const unsigned short* gv0 = Vp + baseI + (size_t)(2 * vkp0) * LDQ + vch0 * 8;
    vreg[0] = *(const short8*)(gv0);
    vreg[1] = *(const short8*)(gv0 + LDQ);
    const unsigned short* gv1 = Vp + baseI + (size_t)(2 * vkp1) * LDQ + vch1 * 8;
    vreg[2] = *(const short8*)(gv1);
    vreg[3] = *(const short8*)(gv1 + LDQ);
  }

  for (int kt = 0; kt < nkt; ++kt) {
    const int cur = kt & 1;
    const int kv0 = kt * 64;

    asm volatile("s_waitcnt vmcnt(0)" ::: "memory");   // K glds landed, V regs ready
    // paired scatter V regs -> Vt[cur] (b32 writes of {key, key+1})
#pragma unroll
    for (int i = 0; i < 2; ++i) {
      int kp = i ? vkp1 : vkp0;
      int ch = i ? vch1 : vch0;
      union { short8 v; unsigned short u[8]; } ua, ub;
      ua.v = vreg[2 * i]; ub.v = vreg[2 * i + 1];
#pragma unroll
      for (int j = 0; j < 8; ++j) {
        int dh = ch * 8 + j;
        int sv = (ch ^ j) & 7;
        unsigned val = (unsigned)ua.u[j] | ((unsigned)ub.u[j] << 16);
        *(unsigned int*)&Vt[cur][dh * 64 + ((2 * kp) ^ (sv << 3))] = val;
      }
    }
    __syncthreads();

    // issue next tile's stage
    if (kt + 1 < nkt) {
      const int kn0 = kv0 + 64;
      const int nb = cur ^ 1;
#pragma unroll
      for (int it = 0; it < 4; ++it) {
        int c = tid + it * 256;
        int key = c >> 4, pos = c & 15;
        int gchunk = pos ^ (key & 7);
        const unsigned short* ga = Kp + baseI + (size_t)(kn0 + key) * LDQ + gchunk * 8;
        __builtin_amdgcn_global_load_lds((const __attribute__((address_space(1))) void*)ga,
                                         (__attribute__((address_space(3))) void*)(&Ks[nb][c * 8]),
                                         16, 0, 0);
      }
      const unsigned short* gv0 = Vp + baseI + (size_t)(kn0 + 2 * vkp0) * LDQ + vch0 * 8;
      vreg[0] = *(const short8*)(gv0);
      vreg[1] = *(const short8*)(gv0 + LDQ);
      const unsigned short* gv1 = Vp + baseI + (size_t)(kn0 + 2 * vkp1) * LDQ + vch1 * 8;
      vreg[2] = *(const short8*)(gv1);
      vreg[3] = *(const short8*)(gv1 + LDQ);
    }

    if (kv0 <= qw + 31) {
      // ---- S^T = K Q^T ----
      f32x4 sacc[2][4] = {};
      __builtin_amdgcn_s_setprio(1);
#pragma unroll
      for (int st = 0; st < 4; ++st) {
        int key = st * 16 + l15;
#pragma unroll
        for (int kk = 0; kk < 4; ++kk) {
          bf16x8 kf = *(const bf16x8*)&Ks[cur][key * 128 + ((kk * 32 + l4 * 8) ^ ((key & 7) << 3))];
          sacc[0][st] = __builtin_amdgcn_mfma_f32_16x16x32_bf16(kf, qf[0][kk], sacc[0][st], 0, 0, 0);
          sacc[1][st] = __builtin_amdgcn_mfma_f32_16x16x32_bf16(kf, qf[1][kk], sacc[1][st], 0, 0, 0);
        }
      }
      __builtin_amdgcn_s_setprio(0);

      // ---- online softmax (defer-max THR=8) ----
      const bool tail = (kv0 + 63 > qw);
      float tmax[2];
#pragma unroll
      for (int qg = 0; qg < 2; ++qg) {
        if (tail) {
          int q = qw + qg * 16 + l15;
#pragma unroll
          for (int st = 0; st < 4; ++st)
#pragma unroll
            for (int r = 0; r < 4; ++r) {
              int key = kv0 + st * 16 + l4 * 4 + r;
              if (key > q) sacc[qg][st][r] = -3.0e38f;
            }
        }
        float a0 = fmaxf(fmaxf(sacc[qg][0][0], sacc[qg][0][1]), fmaxf(sacc[qg][0][2], sacc[qg][0][3]));
        float a1 = fmaxf(fmaxf(sacc[qg][1][0], sacc[qg][1][1]), fmaxf(sacc[qg][1][2], sacc[qg][1][3]));
        float a2 = fmaxf(fmaxf(sacc[qg][2][0], sacc[qg][2][1]), fmaxf(sacc[qg][2][2], sacc[qg][2][3]));
        float a3 = fmaxf(fmaxf(sacc[qg][3][0], sacc[qg][3][1]), fmaxf(sacc[qg][3][2], sacc[qg][3][3]));
        float t = fmaxf(fmaxf(a0, a1), fmaxf(a2, a3));
        t = fmaxf(t, __shfl_xor(t, 16));
        t = fmaxf(t, __shfl_xor(t, 32));
        tmax[qg] = t;
      }
      bool grow = (tmax[0] > m_run[0] + 8.f) || (tmax[1] > m_run[1] + 8.f);
      if (__any(grow)) {
#pragma unroll
        for (int qg = 0; qg < 2; ++qg) {
          float nm = fmaxf(m_run[qg], tmax[qg]);
          float scl = __builtin_amdgcn_exp2f((m_run[qg] - nm) * SC);
          m_run[qg] = nm;
          lp[qg] *= scl;
#pragma unroll
          for (int r = 0; r < 4; ++r) {
            float srow = __shfl(scl, l4 * 4 + r);
#pragma unroll
            for (int df = 0; df < 8; ++df) acc[qg][df][r] *= srow;
          }
        }
      }
#pragma unroll
      for (int qg = 0; qg < 2; ++qg) {
        int q = qg * 16 + l15;
        float ps = 0.f;
#pragma unroll
        for (int st = 0; st < 4; ++st) {
          float p0 = __builtin_amdgcn_exp2f((sacc[qg][st][0] - m_run[qg]) * SC);
          float p1 = __builtin_amdgcn_exp2f((sacc[qg][st][1] - m_run[qg]) * SC);
          float p2 = __builtin_amdgcn_exp2f((sacc[qg][st][2] - m_run[qg]) * SC);
          float p3 = __builtin_amdgcn_exp2f((sacc[qg][st][3] - m_run[qg]) * SC);
          ps += (p0 + p1) + (p2 + p3);
          unsigned w0 = (unsigned)f2bf(p0) | ((unsigned)f2bf(p1) << 16);
          unsigned w1 = (unsigned)f2bf(p2) | ((unsigned)f2bf(p3) << 16);
          int kw0 = st * 8 + l4 * 2;
          Pl[w][q * 32 + (kw0 ^ ((q & 7) << 2))] = w0;
          Pl[w][q * 32 + ((kw0 + 1) ^ ((q & 7) << 2))] = w1;
        }
        lp[qg] += ps;
      }
      // ---- O += P V ----
      __builtin_amdgcn_s_setprio(1);
#pragma unroll
      for (int ks2 = 0; ks2 < 2; ++ks2) {
        int kwb = ks2 * 16 + l4 * 4;
        bf16x8 pa0 = *(const bf16x8*)&Pl[w][l15 * 32 + (kwb ^ ((l15 & 7) << 2))];
        bf16x8 pa1 = *(const bf16x8*)&Pl[w][(16 + l15) * 32 + (kwb ^ ((l15 & 7) << 2))];
#pragma unroll
        for (int df = 0; df < 8; ++df) {
          int dh = df * 16 + l15;
          int sv = ((dh >> 3) ^ dh) & 7;
          bf16x8 vb = *(const bf16x8*)&Vt[cur][dh * 64 + ((ks2 * 32 + l4 * 8) ^ (sv << 3))];
          acc[0][df] = __builtin_amdgcn_mfma_f32_16x16x32_bf16(pa0, vb, acc[0][df], 0, 0, 0);
          acc[1][df] = __builtin_amdgcn_mfma_f32_16x16x32_bf16(pa1, vb, acc[1][df], 0, 0, 0);
        }
      }
      __builtin_amdgcn_s_setprio(0);
    }
  }

#pragma unroll
  for (int qg = 0; qg < 2; ++qg) {
    float t = lp[qg];
    t += __shfl_xor(t, 16);
    t += __shfl_xor(t, 32);
    float linv = 1.0f / t;
#pragma unroll
    for (int r = 0; r < 4; ++r) {
      float lrow = __shfl(linv, l4 * 4 + r);
      int row = qw + qg * 16 + l4 * 4 + r;
#pragma unroll
      for (int df = 0; df < 8; ++df)
        O[baseO + (size_t)row * D_MODEL + df * 16 + l15] = f2bf(acc[qg][df][r] * lrow);
    }
  }
}

// ---------------- launch ----------------
extern "C" void kernel_launch(void* const* d_in, const int* in_sizes, int n_in,
                              void* d_out, int out_size, void* d_ws, size_t ws_size,
                              hipStream_t stream) {
  const float* x  = (const float*)d_in[0];
  const float* Wq = (const float*)d_in[1];
  const float* Wk = (const float*)d_in[2];
  const float* Wv = (const float*)d_in[3];
  const float* Wo = (const float*)d_in[4];
  const float* bo = (const float*)d_in[5];
  float* out = (float*)d_out;

  unsigned short* ws = (unsigned short*)d_ws;
  const size_t XSZ = (size_t)MTOT * D_MODEL;      // 16,777,216
  const size_t WSZ = (size_t)D_MODEL * D_MODEL;   // 4,194,304
  unsigned short* xb   = ws;                       // also reused as attn-out
  unsigned short* Wcat = xb + XSZ;                 // [6144][2048] = Wq|Wk|Wv rows
  unsigned short* Wob  = Wcat + 3 * WSZ;
  unsigned short* QKV  = Wob + WSZ;                // [8192][6144]
  unsigned short* AOb  = xb;

  cvt_bf16_k<<<(int)(XSZ / 8 / 256), 256, 0, stream>>>(x, xb, (int)XSZ);
  dim3 gw((unsigned)(WSZ / 8 / 256), 4);
  cvt_w_k<<<gw, 256, 0, stream>>>(Wq, Wk, Wv, Wo,
                                  Wcat, Wcat + WSZ, Wcat + 2 * WSZ, Wob);

  // fused QKV projection: [8192,2048] x [6144,2048]^T -> [8192,6144]
  dim3 gq(MTOT / 256, LDQ / 256);   // 32 x 24 = 768 blocks (%8==0)
  gemm256<true, false><<<gq, 512, 0, stream>>>(xb, Wcat, QKV, nullptr, MTOT, LDQ, D_MODEL);

  dim3 ga(SEQ / 128, BATCH * NH);   // 16 x 64
  attn_k<<<ga, 256, 0, stream>>>(QKV, QKV + 2048, QKV + 4096, AOb);

  // output projection: [8192,2048] x [2048,2048]^T -> fp32 + bias
  dim3 gg(MTOT / 256, D_MODEL / 256);  // 32 x 8 = 256 blocks (%8==0)
  gemm256<false, true><<<gg, 512, 0, stream>>>(AOb, Wob, out, bo, MTOT, D_MODEL, D_MODEL);
}

// Round 8
// 404.180 us; speedup vs baseline: 3.9143x; 1.3231x over previous
//
#include <hip/hip_runtime.h>
#include <stdint.h>

#define D_MODEL 2048
#define NH 16
#define DH 128
#define BATCH 4
#define SEQ 2048
#define MTOT (BATCH*SEQ)   // 8192
#define LDQ 6144           // fused QKV row stride

typedef __bf16 bf16x8 __attribute__((ext_vector_type(8)));
typedef float f32x4 __attribute__((ext_vector_type(4)));
typedef short short8 __attribute__((ext_vector_type(8)));

static __device__ __forceinline__ unsigned short f2bf(float f) {
  union { float f; unsigned int u; } v; v.f = f;
  return (unsigned short)((v.u + 0x7FFFu + ((v.u >> 16) & 1u)) >> 16);
}

#define FENCEM() asm volatile("" ::: "memory")
#define GBAR() do { FENCEM(); __builtin_amdgcn_s_barrier(); FENCEM(); } while (0)

// ---------------- fp32 -> bf16 conversion ----------------
__global__ __launch_bounds__(256) void cvt_bf16_k(const float* __restrict__ in,
                                                  unsigned short* __restrict__ out, int n) {
  int i = (blockIdx.x * 256 + threadIdx.x) * 8;
  if (i >= n) return;
  float4 a = *(const float4*)(in + i);
  float4 b = *(const float4*)(in + i + 4);
  union { unsigned short u[8]; short8 v; } o;
  o.u[0] = f2bf(a.x); o.u[1] = f2bf(a.y); o.u[2] = f2bf(a.z); o.u[3] = f2bf(a.w);
  o.u[4] = f2bf(b.x); o.u[5] = f2bf(b.y); o.u[6] = f2bf(b.z); o.u[7] = f2bf(b.w);
  *(short8*)(out + i) = o.v;
}

// 4 weight tensors in one dispatch (blockIdx.y selects slice)
__global__ __launch_bounds__(256) void cvt_w_k(const float* __restrict__ w0, const float* __restrict__ w1,
                                               const float* __restrict__ w2, const float* __restrict__ w3,
                                               unsigned short* __restrict__ o0, unsigned short* __restrict__ o1,
                                               unsigned short* __restrict__ o2, unsigned short* __restrict__ o3) {
  const float* src; unsigned short* dst;
  switch (blockIdx.y) {
    case 0: src = w0; dst = o0; break;
    case 1: src = w1; dst = o1; break;
    case 2: src = w2; dst = o2; break;
    default: src = w3; dst = o3; break;
  }
  int i = (blockIdx.x * 256 + threadIdx.x) * 8;
  float4 a = *(const float4*)(src + i);
  float4 b = *(const float4*)(src + i + 4);
  union { unsigned short u[8]; short8 v; } o;
  o.u[0] = f2bf(a.x); o.u[1] = f2bf(a.y); o.u[2] = f2bf(a.z); o.u[3] = f2bf(a.w);
  o.u[4] = f2bf(b.x); o.u[5] = f2bf(b.y); o.u[6] = f2bf(b.z); o.u[7] = f2bf(b.w);
  *(short8*)(dst + i) = o.v;
}

// ---------------- 256x256 8-phase GEMM, 2D-slab XCD mapping ----------------
// 512 threads = 8 waves (2M x 4N); per-wave 128x64; BK=64; LDS 128KB dbuf.
// XCD (xr,xc) in a 4x2 grid owns an (gx/4) x (gy/2) tile slab; within-slab
// traversal is bn-fast so each 1MB A-panel stays L2-resident across 12 blocks.
// Requires gx%4==0 && gy%2==0 (32x24 and 32x8 both satisfy).
template<bool OUT_BF16, bool ADD_BIAS>
__global__ __launch_bounds__(512, 2) void gemm256(const unsigned short* __restrict__ A,
                                                  const unsigned short* __restrict__ B,
                                                  void* __restrict__ C,
                                                  const float* __restrict__ bias,
                                                  int M, int N, int K) {
  __shared__ __align__(16) unsigned short As[2][256 * 64];   // 64KB
  __shared__ __align__(16) unsigned short Bs[2][256 * 64];   // 64KB

  const int tid = threadIdx.x;
  const int lane = tid & 63;
  const int l15 = lane & 15, l4 = lane >> 4;
  const int wid = tid >> 6;
  const int wr = wid >> 2, wc = wid & 3;    // 2 x 4 wave grid

  const int gx = gridDim.x;
  const int id = blockIdx.y * gx + blockIdx.x;
  const int msl = gx >> 2;                  // M-slab width (blocks)
  const int nsl = gridDim.y >> 1;           // N-slab width (blocks)
  const int xcd = id & 7;
  const int lid = id >> 3;
  const int bm = (xcd >> 1) * msl + lid / nsl;
  const int bn = (xcd & 1) * nsl + lid % nsl;

  const int NT = K >> 6;

  const int st_r = tid >> 3;
  const int st_c = (tid & 7) ^ (st_r & 7);
  const int st_ld = st_r * 64 + (tid & 7) * 8;

#define STAGE_A(t, h) do { \
  const int _b = (t) & 1; \
  _Pragma("unroll") \
  for (int _i = 0; _i < 2; ++_i) { \
    const unsigned short* _g = A + (size_t)(bm * 256 + (h) * 128 + _i * 64 + st_r) * K + (t) * 64 + st_c * 8; \
    __builtin_amdgcn_global_load_lds((const __attribute__((address_space(1))) void*)_g, \
        (__attribute__((address_space(3))) void*)(&As[_b][(h) * 8192 + _i * 4096 + st_ld]), 16, 0, 0); \
  } \
} while (0)

#define STAGE_B(t, h) do { \
  const int _b = (t) & 1; \
  _Pragma("unroll") \
  for (int _i = 0; _i < 2; ++_i) { \
    const unsigned short* _g = B + (size_t)(bn * 256 + (h) * 128 + _i * 64 + st_r) * K + (t) * 64 + st_c * 8; \
    __builtin_amdgcn_global_load_lds((const __attribute__((address_space(1))) void*)_g, \
        (__attribute__((address_space(3))) void*)(&Bs[_b][(h) * 8192 + _i * 4096 + st_ld]), 16, 0, 0); \
  } \
} while (0)

#define LDA_F(dst, bufb, mh) do { \
  _Pragma("unroll") \
  for (int _mi = 0; _mi < 4; ++_mi) { \
    int _row = wr * 128 + (mh) * 64 + _mi * 16 + l15; \
    _Pragma("unroll") \
    for (int _kk = 0; _kk < 2; ++_kk) \
      dst[_mi][_kk] = *(const bf16x8*)&As[bufb][_row * 64 + ((_kk * 4 + l4) ^ (l15 & 7)) * 8]; \
  } \
} while (0)

#define LDB_F(dst, bufb, nq) do { \
  _Pragma("unroll") \
  for (int _ni = 0; _ni < 2; ++_ni) { \
    int _row = wc * 64 + (nq) * 32 + _ni * 16 + l15; \
    _Pragma("unroll") \
    for (int _kk = 0; _kk < 2; ++_kk) \
      dst[_ni][_kk] = *(const bf16x8*)&Bs[bufb][_row * 64 + ((_kk * 4 + l4) ^ (l15 & 7)) * 8]; \
  } \
} while (0)

#define PHASE_MFMA(MH, NQ, BFR) do { \
  __builtin_amdgcn_s_setprio(1); \
  _Pragma("unroll") \
  for (int _mi = 0; _mi < 4; ++_mi) { \
    _Pragma("unroll") \
    for (int _ni = 0; _ni < 2; ++_ni) { \
      acc[(MH) * 4 + _mi][(NQ) * 2 + _ni] = __builtin_amdgcn_mfma_f32_16x16x32_bf16( \
          af[_mi][0], BFR[_ni][0], acc[(MH) * 4 + _mi][(NQ) * 2 + _ni], 0, 0, 0); \
      acc[(MH) * 4 + _mi][(NQ) * 2 + _ni] = __builtin_amdgcn_mfma_f32_16x16x32_bf16( \
          af[_mi][1], BFR[_ni][1], acc[(MH) * 4 + _mi][(NQ) * 2 + _ni], 0, 0, 0); \
    } \
  } \
  __builtin_amdgcn_s_setprio(0); \
} while (0)

  f32x4 acc[8][4] = {};

  STAGE_A(0, 0); STAGE_A(0, 1);
  STAGE_B(0, 0); STAGE_B(0, 1);
  if (NT > 1) { STAGE_A(1, 0); STAGE_A(1, 1); }
  if (NT > 1) asm volatile("s_waitcnt vmcnt(4)" ::: "memory");
  else        asm volatile("s_waitcnt vmcnt(0)" ::: "memory");
  GBAR();

  for (int t = 0; t < NT; ++t) {
    const int bufb = t & 1;
    bf16x8 af[4][2], bf0[2][2], bf1[2][2];

    // ---- P1: LDA(h0) 8rd + LDB(bf0,n0) 4rd; stage B(t+1)h0 ----
    LDA_F(af, bufb, 0);
    LDB_F(bf0, bufb, 0);
    if (t + 1 < NT) STAGE_B(t + 1, 0);
    GBAR();
    PHASE_MFMA(0, 0, bf0);
    GBAR();

    // ---- P2: LDB(bf1,n1) 4rd; stage B(t+1)h1 ----
    LDB_F(bf1, bufb, 1);
    if (t + 1 < NT) STAGE_B(t + 1, 1);
    GBAR();
    PHASE_MFMA(0, 1, bf1);
    GBAR();

    // ---- P3: LDA(h1) 8rd ----
    LDA_F(af, bufb, 1);
    GBAR();
    PHASE_MFMA(1, 1, bf1);
    GBAR();   // WAR fence: all A/B reads of tile t complete before A(t+2) staging

    // ---- P4: no ds_reads; stage A(t+2); MFMA(1,0); boundary vmcnt ----
    if (t + 2 < NT) { STAGE_A(t + 2, 0); STAGE_A(t + 2, 1); }
    PHASE_MFMA(1, 0, bf0);
    if (t + 2 < NT) asm volatile("s_waitcnt vmcnt(4)" ::: "memory");
    else            asm volatile("s_waitcnt vmcnt(0)" ::: "memory");
    GBAR();
  }

  const int row0 = bm * 256 + wr * 128;
  const int col0 = bn * 256 + wc * 64;
#pragma unroll
  for (int mi = 0; mi < 8; ++mi) {
#pragma unroll
    for (int ni = 0; ni < 4; ++ni) {
      int col = col0 + ni * 16 + l15;
#pragma unroll
      for (int r = 0; r < 4; ++r) {
        int row = row0 + mi * 16 + l4 * 4 + r;
        float v = acc[mi][ni][r];
        if (ADD_BIAS) v += bias[col];
        if (OUT_BF16)
          ((unsigned short*)C)[(size_t)row * N + col] = f2bf(v);
        else
          ((float*)C)[(size_t)row * N + col] = v;
      }
    }
  }
#undef STAGE_A
#undef STAGE_B
#undef LDA_F
#undef LDB_F
#undef PHASE_MFMA
}

// ---------------- causal flash attention, bh-grouped XCD mapping ----------------
// grid (16, 64) = 1024 blocks; remap so all 16 qt-blocks of one (b,h) land on the
// SAME XCD (K/V = 1MB, L2-resident, read once per XCD instead of 8x). Heavy qt
// still dispatched first. 4 waves x QBLK=32 q-rows, KVBLK=64; V paired-scatter.
__global__ __launch_bounds__(256, 2) void attn_k(const unsigned short* __restrict__ Qp,
                                                 const unsigned short* __restrict__ Kp,
                                                 const unsigned short* __restrict__ Vp,
                                                 unsigned short* __restrict__ O) {
  __shared__ __align__(16) unsigned short Ks[2][64 * 128];   // 32KB dbuf
  __shared__ __align__(16) unsigned short Vt[2][128 * 64];   // 32KB dbuf, [dh][key]
  __shared__ __align__(16) unsigned int   Pl[4][32 * 32];    // 16KB per-wave P

  const int tid = threadIdx.x;
  const int lane = tid & 63;
  const int l15 = lane & 15, l4 = lane >> 4;
  const int w = tid >> 6;

  // XCD-grouping remap: idx -> (bh, qt); hardware XCD = idx%8; same bh => same XCD.
  const int idx = blockIdx.y * gridDim.x + blockIdx.x;
  const int x8 = idx & 7, j = idx >> 3;
  const int bh = x8 * 8 + (j & 7);
  const int qt = 15 - (j >> 3);              // heavy blocks dispatched first
  const int b = bh >> 4, h = bh & 15;

  const size_t baseI = (size_t)b * SEQ * LDQ + (size_t)h * DH;
  const size_t baseO = (size_t)b * SEQ * D_MODEL + (size_t)h * DH;
  const int qw = qt * 128 + w * 32;

  bf16x8 qf[2][4];
#pragma unroll
  for (int qg = 0; qg < 2; ++qg) {
    const unsigned short* qptr = Qp + baseI + (size_t)(qw + qg * 16 + l15) * LDQ;
#pragma unroll
    for (int kk = 0; kk < 4; ++kk)
      qf[qg][kk] = *(const bf16x8*)(qptr + kk * 32 + l4 * 8);
  }

  f32x4 acc[2][8] = {};
  float m_run[2] = {-3.4028235e38f, -3.4028235e38f};
  float lp[2] = {0.f, 0.f};
  const float SC = 0.12751743f;  // (1/sqrt(128)) * log2(e)

  short8 vreg[4];
  const int nkt = 2 * qt + 2;

  // thread constants for V pairing: kp = key-pair index, ch = dh chunk
  const int vkp0 = tid >> 4, vch0 = tid & 15;          // c = tid
  const int vkp1 = (tid + 256) >> 4, vch1 = vch0;      // c = tid + 256

  // ---- prologue: stage kt=0 ----
#pragma unroll
  for (int it = 0; it < 4; ++it) {
    int c = tid + it * 256;
    int key = c >> 4, pos = c & 15;
    int gchunk = pos ^ (key & 7);
    const unsigned short* ga = Kp + baseI + (size_t)key * LDQ + gchunk * 8;
    __builtin_amdgcn_global_load_lds((const __attribute__((address_space(1))) void*)ga,
                                     (__attribute__((address_space(3))) void*)(&Ks[0][c * 8]),
                                     16, 0, 0);
  }
  {
    const unsigned short* gv0 = Vp + baseI + (size_t)(2 * vkp0) * LDQ + vch0 * 8;
    vreg[0] = *(const short8*)(gv0);
    vreg[1] = *(const short8*)(gv0 + LDQ);
    const unsigned short* gv1 = Vp + baseI + (size_t)(2 * vkp1) * LDQ + vch1 * 8;
    vreg[2] = *(const short8*)(gv1);
    vreg[3] = *(const short8*)(gv1 + LDQ);
  }

  for (int kt = 0; kt < nkt; ++kt) {
    const int cur = kt & 1;
    const int kv0 = kt * 64;

    asm volatile("s_waitcnt vmcnt(0)" ::: "memory");   // K glds landed, V regs ready
    // paired scatter V regs -> Vt[cur] (b32 writes of {key, key+1})
#pragma unroll
    for (int i = 0; i < 2; ++i) {
      int kp = i ? vkp1 : vkp0;
      int ch = i ? vch1 : vch0;
      union { short8 v; unsigned short u[8]; } ua, ub;
      ua.v = vreg[2 * i]; ub.v = vreg[2 * i + 1];
#pragma unroll
      for (int j2 = 0; j2 < 8; ++j2) {
        int dh = ch * 8 + j2;
        int sv = (ch ^ j2) & 7;
        unsigned val = (unsigned)ua.u[j2] | ((unsigned)ub.u[j2] << 16);
        *(unsigned int*)&Vt[cur][dh * 64 + ((2 * kp) ^ (sv << 3))] = val;
      }
    }
    __syncthreads();

    // issue next tile's stage
    if (kt + 1 < nkt) {
      const int kn0 = kv0 + 64;
      const int nb = cur ^ 1;
#pragma unroll
      for (int it = 0; it < 4; ++it) {
        int c = tid + it * 256;
        int key = c >> 4, pos = c & 15;
        int gchunk = pos ^ (key & 7);
        const unsigned short* ga = Kp + baseI + (size_t)(kn0 + key) * LDQ + gchunk * 8;
        __builtin_amdgcn_global_load_lds((const __attribute__((address_space(1))) void*)ga,
                                         (__attribute__((address_space(3))) void*)(&Ks[nb][c * 8]),
                                         16, 0, 0);
      }
      const unsigned short* gv0 = Vp + baseI + (size_t)(kn0 + 2 * vkp0) * LDQ + vch0 * 8;
      vreg[0] = *(const short8*)(gv0);
      vreg[1] = *(const short8*)(gv0 + LDQ);
      const unsigned short* gv1 = Vp + baseI + (size_t)(kn0 + 2 * vkp1) * LDQ + vch1 * 8;
      vreg[2] = *(const short8*)(gv1);
      vreg[3] = *(const short8*)(gv1 + LDQ);
    }

    if (kv0 <= qw + 31) {
      // ---- S^T = K Q^T ----
      f32x4 sacc[2][4] = {};
      __builtin_amdgcn_s_setprio(1);
#pragma unroll
      for (int st = 0; st < 4; ++st) {
        int key = st * 16 + l15;
#pragma unroll
        for (int kk = 0; kk < 4; ++kk) {
          bf16x8 kf = *(const bf16x8*)&Ks[cur][key * 128 + ((kk * 32 + l4 * 8) ^ ((key & 7) << 3))];
          sacc[0][st] = __builtin_amdgcn_mfma_f32_16x16x32_bf16(kf, qf[0][kk], sacc[0][st], 0, 0, 0);
          sacc[1][st] = __builtin_amdgcn_mfma_f32_16x16x32_bf16(kf, qf[1][kk], sacc[1][st], 0, 0, 0);
        }
      }
      __builtin_amdgcn_s_setprio(0);

      // ---- online softmax (defer-max THR=8) ----
      const bool tail = (kv0 + 63 > qw);
      float tmax[2];
#pragma unroll
      for (int qg = 0; qg < 2; ++qg) {
        if (tail) {
          int q = qw + qg * 16 + l15;
#pragma unroll
          for (int st = 0; st < 4; ++st)
#pragma unroll
            for (int r = 0; r < 4; ++r) {
              int key = kv0 + st * 16 + l4 * 4 + r;
              if (key > q) sacc[qg][st][r] = -3.0e38f;
            }
        }
        float a0 = fmaxf(fmaxf(sacc[qg][0][0], sacc[qg][0][1]), fmaxf(sacc[qg][0][2], sacc[qg][0][3]));
        float a1 = fmaxf(fmaxf(sacc[qg][1][0], sacc[qg][1][1]), fmaxf(sacc[qg][1][2], sacc[qg][1][3]));
        float a2 = fmaxf(fmaxf(sacc[qg][2][0], sacc[qg][2][1]), fmaxf(sacc[qg][2][2], sacc[qg][2][3]));
        float a3 = fmaxf(fmaxf(sacc[qg][3][0], sacc[qg][3][1]), fmaxf(sacc[qg][3][2], sacc[qg][3][3]));
        float t = fmaxf(fmaxf(a0, a1), fmaxf(a2, a3));
        t = fmaxf(t, __shfl_xor(t, 16));
        t = fmaxf(t, __shfl_xor(t, 32));
        tmax[qg] = t;
      }
      bool grow = (tmax[0] > m_run[0] + 8.f) || (tmax[1] > m_run[1] + 8.f);
      if (__any(grow)) {
#pragma unroll
        for (int qg = 0; qg < 2; ++qg) {
          float nm = fmaxf(m_run[qg], tmax[qg]);
          float scl = __builtin_amdgcn_exp2f((m_run[qg] - nm) * SC);
          m_run[qg] = nm;
          lp[qg] *= scl;
#pragma unroll
          for (int r = 0; r < 4; ++r) {
            float srow = __shfl(scl, l4 * 4 + r);
#pragma unroll
            for (int df = 0; df < 8; ++df) acc[qg][df][r] *= srow;
          }
        }
      }
#pragma unroll
      for (int qg = 0; qg < 2; ++qg) {
        int q = qg * 16 + l15;
        float ps = 0.f;
#pragma unroll
        for (int st = 0; st < 4; ++st) {
          float p0 = __builtin_amdgcn_exp2f((sacc[qg][st][0] - m_run[qg]) * SC);
          float p1 = __builtin_amdgcn_exp2f((sacc[qg][st][1] - m_run[qg]) * SC);
          float p2 = __builtin_amdgcn_exp2f((sacc[qg][st][2] - m_run[qg]) * SC);
          float p3 = __builtin_amdgcn_exp2f((sacc[qg][st][3] - m_run[qg]) * SC);
          ps += (p0 + p1) + (p2 + p3);
          unsigned w0 = (unsigned)f2bf(p0) | ((unsigned)f2bf(p1) << 16);
          unsigned w1 = (unsigned)f2bf(p2) | ((unsigned)f2bf(p3) << 16);
          int kw0 = st * 8 + l4 * 2;
          Pl[w][q * 32 + (kw0 ^ ((q & 7) << 2))] = w0;
          Pl[w][q * 32 + ((kw0 + 1) ^ ((q & 7) << 2))] = w1;
        }
        lp[qg] += ps;
      }
      // ---- O += P V ----
      __builtin_amdgcn_s_setprio(1);
#pragma unroll
      for (int ks2 = 0; ks2 < 2; ++ks2) {
        int kwb = ks2 * 16 + l4 * 4;
        bf16x8 pa0 = *(const bf16x8*)&Pl[w][l15 * 32 + (kwb ^ ((l15 & 7) << 2))];
        bf16x8 pa1 = *(const bf16x8*)&Pl[w][(16 + l15) * 32 + (kwb ^ ((l15 & 7) << 2))];
#pragma unroll
        for (int df = 0; df < 8; ++df) {
          int dh = df * 16 + l15;
          int sv = ((dh >> 3) ^ dh) & 7;
          bf16x8 vb = *(const bf16x8*)&Vt[cur][dh * 64 + ((ks2 * 32 + l4 * 8) ^ (sv << 3))];
          acc[0][df] = __builtin_amdgcn_mfma_f32_16x16x32_bf16(pa0, vb, acc[0][df], 0, 0, 0);
          acc[1][df] = __builtin_amdgcn_mfma_f32_16x16x32_bf16(pa1, vb, acc[1][df], 0, 0, 0);
        }
      }
      __builtin_amdgcn_s_setprio(0);
    }
  }

#pragma unroll
  for (int qg = 0; qg < 2; ++qg) {
    float t = lp[qg];
    t += __shfl_xor(t, 16);
    t += __shfl_xor(t, 32);
    float linv = 1.0f / t;
#pragma unroll
    for (int r = 0; r < 4; ++r) {
      float lrow = __shfl(linv, l4 * 4 + r);
      int row = qw + qg * 16 + l4 * 4 + r;
#pragma unroll
      for (int df = 0; df < 8; ++df)
        O[baseO + (size_t)row * D_MODEL + df * 16 + l15] = f2bf(acc[qg][df][r] * lrow);
    }
  }
}

// ---------------- launch ----------------
extern "C" void kernel_launch(void* const* d_in, const int* in_sizes, int n_in,
                              void* d_out, int out_size, void* d_ws, size_t ws_size,
                              hipStream_t stream) {
  const float* x  = (const float*)d_in[0];
  const float* Wq = (const float*)d_in[1];
  const float* Wk = (const float*)d_in[2];
  const float* Wv = (const float*)d_in[3];
  const float* Wo = (const float*)d_in[4];
  const float* bo = (const float*)d_in[5];
  float* out = (float*)d_out;

  unsigned short* ws = (unsigned short*)d_ws;
  const size_t XSZ = (size_t)MTOT * D_MODEL;      // 16,777,216
  const size_t WSZ = (size_t)D_MODEL * D_MODEL;   // 4,194,304
  unsigned short* xb   = ws;                       // also reused as attn-out
  unsigned short* Wcat = xb + XSZ;                 // [6144][2048] = Wq|Wk|Wv rows
  unsigned short* Wob  = Wcat + 3 * WSZ;
  unsigned short* QKV  = Wob + WSZ;                // [8192][6144]
  unsigned short* AOb  = xb;

  cvt_bf16_k<<<(int)(XSZ / 8 / 256), 256, 0, stream>>>(x, xb, (int)XSZ);
  dim3 gw((unsigned)(WSZ / 8 / 256), 4);
  cvt_w_k<<<gw, 256, 0, stream>>>(Wq, Wk, Wv, Wo,
                                  Wcat, Wcat + WSZ, Wcat + 2 * WSZ, Wob);

  // fused QKV projection: [8192,2048] x [6144,2048]^T -> [8192,6144]
  dim3 gq(MTOT / 256, LDQ / 256);   // 32 x 24 = 768 blocks
  gemm256<true, false><<<gq, 512, 0, stream>>>(xb, Wcat, QKV, nullptr, MTOT, LDQ, D_MODEL);

  dim3 ga(SEQ / 128, BATCH * NH);   // 16 x 64
  attn_k<<<ga, 256, 0, stream>>>(QKV, QKV + 2048, QKV + 4096, AOb);

  // output projection: [8192,2048] x [2048,2048]^T -> fp32 + bias
  dim3 gg(MTOT / 256, D_MODEL / 256);  // 32 x 8 = 256 blocks
  gemm256<false, true><<<gg, 512, 0, stream>>>(AOb, Wob, out, bo, MTOT, D_MODEL, D_MODEL);
}

// Round 9
// 391.166 us; speedup vs baseline: 4.0445x; 1.0333x over previous
//
#include <hip/hip_runtime.h>
#include <stdint.h>

#define D_MODEL 2048
#define NH 16
#define DH 128
#define BATCH 4
#define SEQ 2048
#define MTOT (BATCH*SEQ)   // 8192
#define LDQ 6144           // fused QKV row stride

typedef __bf16 bf16x8 __attribute__((ext_vector_type(8)));
typedef float f32x4 __attribute__((ext_vector_type(4)));
typedef short short8 __attribute__((ext_vector_type(8)));

static __device__ __forceinline__ unsigned short f2bf(float f) {
  union { float f; unsigned int u; } v; v.f = f;
  return (unsigned short)((v.u + 0x7FFFu + ((v.u >> 16) & 1u)) >> 16);
}

#define FENCEM() asm volatile("" ::: "memory")
#define GBAR() do { FENCEM(); __builtin_amdgcn_s_barrier(); FENCEM(); } while (0)

// ---------------- fp32 -> bf16 conversion ----------------
__global__ __launch_bounds__(256) void cvt_bf16_k(const float* __restrict__ in,
                                                  unsigned short* __restrict__ out, int n) {
  int i = (blockIdx.x * 256 + threadIdx.x) * 8;
  if (i >= n) return;
  float4 a = *(const float4*)(in + i);
  float4 b = *(const float4*)(in + i + 4);
  union { unsigned short u[8]; short8 v; } o;
  o.u[0] = f2bf(a.x); o.u[1] = f2bf(a.y); o.u[2] = f2bf(a.z); o.u[3] = f2bf(a.w);
  o.u[4] = f2bf(b.x); o.u[5] = f2bf(b.y); o.u[6] = f2bf(b.z); o.u[7] = f2bf(b.w);
  *(short8*)(out + i) = o.v;
}

// 4 weight tensors in one dispatch (blockIdx.y selects slice)
__global__ __launch_bounds__(256) void cvt_w_k(const float* __restrict__ w0, const float* __restrict__ w1,
                                               const float* __restrict__ w2, const float* __restrict__ w3,
                                               unsigned short* __restrict__ o0, unsigned short* __restrict__ o1,
                                               unsigned short* __restrict__ o2, unsigned short* __restrict__ o3) {
  const float* src; unsigned short* dst;
  switch (blockIdx.y) {
    case 0: src = w0; dst = o0; break;
    case 1: src = w1; dst = o1; break;
    case 2: src = w2; dst = o2; break;
    default: src = w3; dst = o3; break;
  }
  int i = (blockIdx.x * 256 + threadIdx.x) * 8;
  float4 a = *(const float4*)(src + i);
  float4 b = *(const float4*)(src + i + 4);
  union { unsigned short u[8]; short8 v; } o;
  o.u[0] = f2bf(a.x); o.u[1] = f2bf(a.y); o.u[2] = f2bf(a.z); o.u[3] = f2bf(a.w);
  o.u[4] = f2bf(b.x); o.u[5] = f2bf(b.y); o.u[6] = f2bf(b.z); o.u[7] = f2bf(b.w);
  *(short8*)(dst + i) = o.v;
}

// ---------------- 256x256 GEMM, 2-barrier/K-tile, 2D-slab XCD mapping ----------------
// 512 threads = 8 waves (2M x 4N); per-wave 128x64; BK=64; LDS 128KB dbuf (1 block/CU).
// Barriers per K-tile: (i) lgkmcnt(0)+GBAR = WAR fence before A(t+2) stages into the
// current buffer; (ii) vmcnt(4)+GBAR = tile-end visibility (A(t+1)+B(t+1) landed,
// A(t+2) stays in flight). All other inter-phase barriers removed: the regions between
// them are LDS reads of the current buffer only; B(t+1) stages target the other buffer.
// Read patterns / swizzle / stage protocol byte-identical to the 0-conflict verified set.
template<bool OUT_BF16, bool ADD_BIAS>
__global__ __launch_bounds__(512, 2) void gemm256(const unsigned short* __restrict__ A,
                                                  const unsigned short* __restrict__ B,
                                                  void* __restrict__ C,
                                                  const float* __restrict__ bias,
                                                  int M, int N, int K) {
  __shared__ __align__(16) unsigned short As[2][256 * 64];   // 64KB
  __shared__ __align__(16) unsigned short Bs[2][256 * 64];   // 64KB

  const int tid = threadIdx.x;
  const int lane = tid & 63;
  const int l15 = lane & 15, l4 = lane >> 4;
  const int wid = tid >> 6;
  const int wr = wid >> 2, wc = wid & 3;    // 2 x 4 wave grid

  const int gx = gridDim.x;
  const int id = blockIdx.y * gx + blockIdx.x;
  const int msl = gx >> 2;                  // M-slab width (blocks)
  const int nsl = gridDim.y >> 1;           // N-slab width (blocks)
  const int xcd = id & 7;
  const int lid = id >> 3;
  const int bm = (xcd >> 1) * msl + lid / nsl;
  const int bn = (xcd & 1) * nsl + lid % nsl;

  const int NT = K >> 6;

  const int st_r = tid >> 3;
  const int st_c = (tid & 7) ^ (st_r & 7);
  const int st_ld = st_r * 64 + (tid & 7) * 8;

#define STAGE_A(t, h) do { \
  const int _b = (t) & 1; \
  _Pragma("unroll") \
  for (int _i = 0; _i < 2; ++_i) { \
    const unsigned short* _g = A + (size_t)(bm * 256 + (h) * 128 + _i * 64 + st_r) * K + (t) * 64 + st_c * 8; \
    __builtin_amdgcn_global_load_lds((const __attribute__((address_space(1))) void*)_g, \
        (__attribute__((address_space(3))) void*)(&As[_b][(h) * 8192 + _i * 4096 + st_ld]), 16, 0, 0); \
  } \
} while (0)

#define STAGE_B(t, h) do { \
  const int _b = (t) & 1; \
  _Pragma("unroll") \
  for (int _i = 0; _i < 2; ++_i) { \
    const unsigned short* _g = B + (size_t)(bn * 256 + (h) * 128 + _i * 64 + st_r) * K + (t) * 64 + st_c * 8; \
    __builtin_amdgcn_global_load_lds((const __attribute__((address_space(1))) void*)_g, \
        (__attribute__((address_space(3))) void*)(&Bs[_b][(h) * 8192 + _i * 4096 + st_ld]), 16, 0, 0); \
  } \
} while (0)

#define LDA_F(dst, bufb, mh) do { \
  _Pragma("unroll") \
  for (int _mi = 0; _mi < 4; ++_mi) { \
    int _row = wr * 128 + (mh) * 64 + _mi * 16 + l15; \
    _Pragma("unroll") \
    for (int _kk = 0; _kk < 2; ++_kk) \
      dst[_mi][_kk] = *(const bf16x8*)&As[bufb][_row * 64 + ((_kk * 4 + l4) ^ (l15 & 7)) * 8]; \
  } \
} while (0)

#define LDB_F(dst, bufb, nq) do { \
  _Pragma("unroll") \
  for (int _ni = 0; _ni < 2; ++_ni) { \
    int _row = wc * 64 + (nq) * 32 + _ni * 16 + l15; \
    _Pragma("unroll") \
    for (int _kk = 0; _kk < 2; ++_kk) \
      dst[_ni][_kk] = *(const bf16x8*)&Bs[bufb][_row * 64 + ((_kk * 4 + l4) ^ (l15 & 7)) * 8]; \
  } \
} while (0)

#define PHASE_MFMA(MH, NQ, BFR) do { \
  _Pragma("unroll") \
  for (int _mi = 0; _mi < 4; ++_mi) { \
    _Pragma("unroll") \
    for (int _ni = 0; _ni < 2; ++_ni) { \
      acc[(MH) * 4 + _mi][(NQ) * 2 + _ni] = __builtin_amdgcn_mfma_f32_16x16x32_bf16( \
          af[_mi][0], BFR[_ni][0], acc[(MH) * 4 + _mi][(NQ) * 2 + _ni], 0, 0, 0); \
      acc[(MH) * 4 + _mi][(NQ) * 2 + _ni] = __builtin_amdgcn_mfma_f32_16x16x32_bf16( \
          af[_mi][1], BFR[_ni][1], acc[(MH) * 4 + _mi][(NQ) * 2 + _ni], 0, 0, 0); \
    } \
  } \
} while (0)

  f32x4 acc[8][4] = {};

  STAGE_A(0, 0); STAGE_A(0, 1);
  STAGE_B(0, 0); STAGE_B(0, 1);
  if (NT > 1) { STAGE_A(1, 0); STAGE_A(1, 1); }
  if (NT > 1) asm volatile("s_waitcnt vmcnt(4)" ::: "memory");
  else        asm volatile("s_waitcnt vmcnt(0)" ::: "memory");
  GBAR();

  for (int t = 0; t < NT; ++t) {
    const int bufb = t & 1;
    bf16x8 af[4][2], bf0[2][2], bf1[2][2];

    // ---- region 1: all loads for m-half0 + both B quads; spread B(t+1) stages ----
    LDA_F(af, bufb, 0);
    LDB_F(bf0, bufb, 0);
    LDB_F(bf1, bufb, 1);
    if (t + 1 < NT) { STAGE_B(t + 1, 0); STAGE_B(t + 1, 1); }
    __builtin_amdgcn_s_setprio(1);
    PHASE_MFMA(0, 0, bf0);
    PHASE_MFMA(0, 1, bf1);
    __builtin_amdgcn_s_setprio(0);

    // ---- m-half1 loads (same buffer, read-only: no barrier needed before) ----
    LDA_F(af, bufb, 1);
    asm volatile("s_waitcnt lgkmcnt(0)" ::: "memory");   // my A-reads of buf t done
    GBAR();                                              // WAR: ALL waves' reads done

    // ---- region 2: stage A(t+2) into now-dead A region; remaining MFMA ----
    if (t + 2 < NT) { STAGE_A(t + 2, 0); STAGE_A(t + 2, 1); }
    __builtin_amdgcn_s_setprio(1);
    PHASE_MFMA(1, 1, bf1);
    PHASE_MFMA(1, 0, bf0);
    __builtin_amdgcn_s_setprio(0);
    if (t + 2 < NT) asm volatile("s_waitcnt vmcnt(4)" ::: "memory");
    else            asm volatile("s_waitcnt vmcnt(0)" ::: "memory");
    GBAR();   // tile boundary: A(t+1)+B(t+1) landed & visible; A(t+2) in flight
  }

  const int row0 = bm * 256 + wr * 128;
  const int col0 = bn * 256 + wc * 64;
#pragma unroll
  for (int mi = 0; mi < 8; ++mi) {
#pragma unroll
    for (int ni = 0; ni < 4; ++ni) {
      int col = col0 + ni * 16 + l15;
#pragma unroll
      for (int r = 0; r < 4; ++r) {
        int row = row0 + mi * 16 + l4 * 4 + r;
        float v = acc[mi][ni][r];
        if (ADD_BIAS) v += bias[col];
        if (OUT_BF16)
          ((unsigned short*)C)[(size_t)row * N + col] = f2bf(v);
        else
          ((float*)C)[(size_t)row * N + col] = v;
      }
    }
  }
#undef STAGE_A
#undef STAGE_B
#undef LDA_F
#undef LDB_F
#undef PHASE_MFMA
}

// ---------------- causal flash attention, bh-grouped XCD mapping (r8 verified) ----------------
__global__ __launch_bounds__(256, 2) void attn_k(const unsigned short* __restrict__ Qp,
                                                 const unsigned short* __restrict__ Kp,
                                                 const unsigned short* __restrict__ Vp,
                                                 unsigned short* __restrict__ O) {
  __shared__ __align__(16) unsigned short Ks[2][64 * 128];   // 32KB dbuf
  __shared__ __align__(16) unsigned short Vt[2][128 * 64];   // 32KB dbuf, [dh][key]
  __shared__ __align__(16) unsigned int   Pl[4][32 * 32];    // 16KB per-wave P

  const int tid = threadIdx.x;
  const int lane = tid & 63;
  const int l15 = lane & 15, l4 = lane >> 4;
  const int w = tid >> 6;

  // XCD-grouping remap: idx -> (bh, qt); hardware XCD = idx%8; same bh => same XCD.
  const int idx = blockIdx.y * gridDim.x + blockIdx.x;
  const int x8 = idx & 7, j = idx >> 3;
  const int bh = x8 * 8 + (j & 7);
  const int qt = 15 - (j >> 3);              // heavy blocks dispatched first
  const int b = bh >> 4, h = bh & 15;

  const size_t baseI = (size_t)b * SEQ * LDQ + (size_t)h * DH;
  const size_t baseO = (size_t)b * SEQ * D_MODEL + (size_t)h * DH;
  const int qw = qt * 128 + w * 32;

  bf16x8 qf[2][4];
#pragma unroll
  for (int qg = 0; qg < 2; ++qg) {
    const unsigned short* qptr = Qp + baseI + (size_t)(qw + qg * 16 + l15) * LDQ;
#pragma unroll
    for (int kk = 0; kk < 4; ++kk)
      qf[qg][kk] = *(const bf16x8*)(qptr + kk * 32 + l4 * 8);
  }

  f32x4 acc[2][8] = {};
  float m_run[2] = {-3.4028235e38f, -3.4028235e38f};
  float lp[2] = {0.f, 0.f};
  const float SC = 0.12751743f;  // (1/sqrt(128)) * log2(e)

  short8 vreg[4];
  const int nkt = 2 * qt + 2;

  const int vkp0 = tid >> 4, vch0 = tid & 15;
  const int vkp1 = (tid + 256) >> 4, vch1 = vch0;

#pragma unroll
  for (int it = 0; it < 4; ++it) {
    int c = tid + it * 256;
    int key = c >> 4, pos = c & 15;
    int gchunk = pos ^ (key & 7);
    const unsigned short* ga = Kp + baseI + (size_t)key * LDQ + gchunk * 8;
    __builtin_amdgcn_global_load_lds((const __attribute__((address_space(1))) void*)ga,
                                     (__attribute__((address_space(3))) void*)(&Ks[0][c * 8]),
                                     16, 0, 0);
  }
  {
    const unsigned short* gv0 = Vp + baseI + (size_t)(2 * vkp0) * LDQ + vch0 * 8;
    vreg[0] = *(const short8*)(gv0);
    vreg[1] = *(const short8*)(gv0 + LDQ);
    const unsigned short* gv1 = Vp + baseI + (size_t)(2 * vkp1) * LDQ + vch1 * 8;
    vreg[2] = *(const short8*)(gv1);
    vreg[3] = *(const short8*)(gv1 + LDQ);
  }

  for (int kt = 0; kt < nkt; ++kt) {
    const int cur = kt & 1;
    const int kv0 = kt * 64;

    asm volatile("s_waitcnt vmcnt(0)" ::: "memory");
#pragma unroll
    for (int i = 0; i < 2; ++i) {
      int kp = i ? vkp1 : vkp0;
      int ch = i ? vch1 : vch0;
      union { short8 v; unsigned short u[8]; } ua, ub;
      ua.v = vreg[2 * i]; ub.v = vreg[2 * i + 1];
#pragma unroll
      for (int j2 = 0; j2 < 8; ++j2) {
        int dh = ch * 8 + j2;
        int sv = (ch ^ j2) & 7;
        unsigned val = (unsigned)ua.u[j2] | ((unsigned)ub.u[j2] << 16);
        *(unsigned int*)&Vt[cur][dh * 64 + ((2 * kp) ^ (sv << 3))] = val;
      }
    }
    __syncthreads();

    if (kt + 1 < nkt) {
      const int kn0 = kv0 + 64;
      const int nb = cur ^ 1;
#pragma unroll
      for (int it = 0; it < 4; ++it) {
        int c = tid + it * 256;
        int key = c >> 4, pos = c & 15;
        int gchunk = pos ^ (key & 7);
        const unsigned short* ga = Kp + baseI + (size_t)(kn0 + key) * LDQ + gchunk * 8;
        __builtin_amdgcn_global_load_lds((const __attribute__((address_space(1))) void*)ga,
                                         (__attribute__((address_space(3))) void*)(&Ks[nb][c * 8]),
                                         16, 0, 0);
      }
      const unsigned short* gv0 = Vp + baseI + (size_t)(kn0 + 2 * vkp0) * LDQ + vch0 * 8;
      vreg[0] = *(const short8*)(gv0);
      vreg[1] = *(const short8*)(gv0 + LDQ);
      const unsigned short* gv1 = Vp + baseI + (size_t)(kn0 + 2 * vkp1) * LDQ + vch1 * 8;
      vreg[2] = *(const short8*)(gv1);
      vreg[3] = *(const short8*)(gv1 + LDQ);
    }

    if (kv0 <= qw + 31) {
      f32x4 sacc[2][4] = {};
      __builtin_amdgcn_s_setprio(1);
#pragma unroll
      for (int st = 0; st < 4; ++st) {
        int key = st * 16 + l15;
#pragma unroll
        for (int kk = 0; kk < 4; ++kk) {
          bf16x8 kf = *(const bf16x8*)&Ks[cur][key * 128 + ((kk * 32 + l4 * 8) ^ ((key & 7) << 3))];
          sacc[0][st] = __builtin_amdgcn_mfma_f32_16x16x32_bf16(kf, qf[0][kk], sacc[0][st], 0, 0, 0);
          sacc[1][st] = __builtin_amdgcn_mfma_f32_16x16x32_bf16(kf, qf[1][kk], sacc[1][st], 0, 0, 0);
        }
      }
      __builtin_amdgcn_s_setprio(0);

      const bool tail = (kv0 + 63 > qw);
      float tmax[2];
#pragma unroll
      for (int qg = 0; qg < 2; ++qg) {
        if (tail) {
          int q = qw + qg * 16 + l15;
#pragma unroll
          for (int st = 0; st < 4; ++st)
#pragma unroll
            for (int r = 0; r < 4; ++r) {
              int key = kv0 + st * 16 + l4 * 4 + r;
              if (key > q) sacc[qg][st][r] = -3.0e38f;
            }
        }
        float a0 = fmaxf(fmaxf(sacc[qg][0][0], sacc[qg][0][1]), fmaxf(sacc[qg][0][2], sacc[qg][0][3]));
        float a1 = fmaxf(fmaxf(sacc[qg][1][0], sacc[qg][1][1]), fmaxf(sacc[qg][1][2], sacc[qg][1][3]));
        float a2 = fmaxf(fmaxf(sacc[qg][2][0], sacc[qg][2][1]), fmaxf(sacc[qg][2][2], sacc[qg][2][3]));
        float a3 = fmaxf(fmaxf(sacc[qg][3][0], sacc[qg][3][1]), fmaxf(sacc[qg][3][2], sacc[qg][3][3]));
        float t = fmaxf(fmaxf(a0, a1), fmaxf(a2, a3));
        t = fmaxf(t, __shfl_xor(t, 16));
        t = fmaxf(t, __shfl_xor(t, 32));
        tmax[qg] = t;
      }
      bool grow = (tmax[0] > m_run[0] + 8.f) || (tmax[1] > m_run[1] + 8.f);
      if (__any(grow)) {
#pragma unroll
        for (int qg = 0; qg < 2; ++qg) {
          float nm = fmaxf(m_run[qg], tmax[qg]);
          float scl = __builtin_amdgcn_exp2f((m_run[qg] - nm) * SC);
          m_run[qg] = nm;
          lp[qg] *= scl;
#pragma unroll
          for (int r = 0; r < 4; ++r) {
            float srow = __shfl(scl, l4 * 4 + r);
#pragma unroll
            for (int df = 0; df < 8; ++df) acc[qg][df][r] *= srow;
          }
        }
      }
#pragma unroll
      for (int qg = 0; qg < 2; ++qg) {
        int q = qg * 16 + l15;
        float ps = 0.f;
#pragma unroll
        for (int st = 0; st < 4; ++st) {
          float p0 = __builtin_amdgcn_exp2f((sacc[qg][st][0] - m_run[qg]) * SC);
          float p1 = __builtin_amdgcn_exp2f((sacc[qg][st][1] - m_run[qg]) * SC);
          float p2 = __builtin_amdgcn_exp2f((sacc[qg][st][2] - m_run[qg]) * SC);
          float p3 = __builtin_amdgcn_exp2f((sacc[qg][st][3] - m_run[qg]) * SC);
          ps += (p0 + p1) + (p2 + p3);
          unsigned w0 = (unsigned)f2bf(p0) | ((unsigned)f2bf(p1) << 16);
          unsigned w1 = (unsigned)f2bf(p2) | ((unsigned)f2bf(p3) << 16);
          int kw0 = st * 8 + l4 * 2;
          Pl[w][q * 32 + (kw0 ^ ((q & 7) << 2))] = w0;
          Pl[w][q * 32 + ((kw0 + 1) ^ ((q & 7) << 2))] = w1;
        }
        lp[qg] += ps;
      }
      __builtin_amdgcn_s_setprio(1);
#pragma unroll
      for (int ks2 = 0; ks2 < 2; ++ks2) {
        int kwb = ks2 * 16 + l4 * 4;
        bf16x8 pa0 = *(const bf16x8*)&Pl[w][l15 * 32 + (kwb ^ ((l15 & 7) << 2))];
        bf16x8 pa1 = *(const bf16x8*)&Pl[w][(16 + l15) * 32 + (kwb ^ ((l15 & 7) << 2))];
#pragma unroll
        for (int df = 0; df < 8; ++df) {
          int dh = df * 16 + l15;
          int sv = ((dh >> 3) ^ dh) & 7;
          bf16x8 vb = *(const bf16x8*)&Vt[cur][dh * 64 + ((ks2 * 32 + l4 * 8) ^ (sv << 3))];
          acc[0][df] = __builtin_amdgcn_mfma_f32_16x16x32_bf16(pa0, vb, acc[0][df], 0, 0, 0);
          acc[1][df] = __builtin_amdgcn_mfma_f32_16x16x32_bf16(pa1, vb, acc[1][df], 0, 0, 0);
        }
      }
      __builtin_amdgcn_s_setprio(0);
    }
  }

#pragma unroll
  for (int qg = 0; qg < 2; ++qg) {
    float t = lp[qg];
    t += __shfl_xor(t, 16);
    t += __shfl_xor(t, 32);
    float linv = 1.0f / t;
#pragma unroll
    for (int r = 0; r < 4; ++r) {
      float lrow = __shfl(linv, l4 * 4 + r);
      int row = qw + qg * 16 + l4 * 4 + r;
#pragma unroll
      for (int df = 0; df < 8; ++df)
        O[baseO + (size_t)row * D_MODEL + df * 16 + l15] = f2bf(acc[qg][df][r] * lrow);
    }
  }
}

// ---------------- launch ----------------
extern "C" void kernel_launch(void* const* d_in, const int* in_sizes, int n_in,
                              void* d_out, int out_size, void* d_ws, size_t ws_size,
                              hipStream_t stream) {
  const float* x  = (const float*)d_in[0];
  const float* Wq = (const float*)d_in[1];
  const float* Wk = (const float*)d_in[2];
  const float* Wv = (const float*)d_in[3];
  const float* Wo = (const float*)d_in[4];
  const float* bo = (const float*)d_in[5];
  float* out = (float*)d_out;

  unsigned short* ws = (unsigned short*)d_ws;
  const size_t XSZ = (size_t)MTOT * D_MODEL;      // 16,777,216
  const size_t WSZ = (size_t)D_MODEL * D_MODEL;   // 4,194,304
  unsigned short* xb   = ws;                       // also reused as attn-out
  unsigned short* Wcat = xb + XSZ;                 // [6144][2048] = Wq|Wk|Wv rows
  unsigned short* Wob  = Wcat + 3 * WSZ;
  unsigned short* QKV  = Wob + WSZ;                // [8192][6144]
  unsigned short* AOb  = xb;

  cvt_bf16_k<<<(int)(XSZ / 8 / 256), 256, 0, stream>>>(x, xb, (int)XSZ);
  dim3 gw((unsigned)(WSZ / 8 / 256), 4);
  cvt_w_k<<<gw, 256, 0, stream>>>(Wq, Wk, Wv, Wo,
                                  Wcat, Wcat + WSZ, Wcat + 2 * WSZ, Wob);

  // fused QKV projection: [8192,2048] x [6144,2048]^T -> [8192,6144]
  dim3 gq(MTOT / 256, LDQ / 256);   // 32 x 24 = 768 blocks
  gemm256<true, false><<<gq, 512, 0, stream>>>(xb, Wcat, QKV, nullptr, MTOT, LDQ, D_MODEL);

  dim3 ga(SEQ / 128, BATCH * NH);   // 16 x 64
  attn_k<<<ga, 256, 0, stream>>>(QKV, QKV + 2048, QKV + 4096, AOb);

  // output projection: [8192,2048] x [2048,2048]^T -> fp32 + bias
  dim3 gg(MTOT / 256, D_MODEL / 256);  // 32 x 8 = 256 blocks
  gemm256<false, true><<<gg, 512, 0, stream>>>(AOb, Wob, out, bo, MTOT, D_MODEL, D_MODEL);
}